// Round 4
// baseline (412.996 us; speedup 1.0000x reference)
//
#include <hip/hip_runtime.h>
#include <stdint.h>

#define GRAPHS 256
#define NPG    512
#define EPG    8192

typedef __attribute__((ext_vector_type(8))) short s16x8;
typedef __attribute__((ext_vector_type(4))) float f32x4;

__device__ __forceinline__ float bf2f(unsigned short u){
  union { unsigned int i; float f; } c; c.i = ((unsigned int)u)<<16; return c.f;
}
__device__ __forceinline__ unsigned short f2bf(float f){
  union { float f; unsigned int i; } c; c.f = f;
  unsigned int r = c.i + 0x7fffu + ((c.i>>16)&1u);   // RNE (software; do NOT
  return (unsigned short)(r>>16);                    // use v_cvt_pk_bf16_f32)
}

// ------- tiny prep: EW1T + W2F (bit-identical) + zero d_out ----------------
__global__ __launch_bounds__(128) void k_prep(const float* __restrict__ emb,
      const float* __restrict__ W1, const float* __restrict__ W2,
      unsigned short* __restrict__ EW1T, unsigned short* __restrict__ W2F,
      float* __restrict__ outz){
  const int b = blockIdx.x, tid = threadIdx.x;
  outz[b*128 + tid] = 0.f;                       // out zero (k_half atomicAdds)
  if (tid < 32){                                 // EW1T: serial f32 dot
    const int gid = b*32 + tid;
    const int t = gid>>7, c = gid&127;
    float acc=0.f;
    #pragma unroll 4
    for (int k=0;k<128;k++) acc += emb[t*128+k]*W1[k*128+c];
    EW1T[c*64+t]=f2bf(acc);
  } else if (tid >= 64){                         // W2F fragment order
    const int i = b*64 + (tid-64);
    const int ks = i>>12, nt=(i>>9)&7, ln=(i>>3)&63, j=i&7;
    const int k = ks*32 + (ln>>4)*8 + j;
    const int n = nt*16 + (ln&15);
    W2F[i] = f2bf(W2[k*128+n]);
  }
}

// ---------------- fused kernel: 1 block = (graph, dst-half) ----------------
// Layer-1 + H2 computed for ALL 512 nodes (duplicated across the graph's two
// blocks — cheap); layer-2 accumulates only this block's 256 dst rows, so the
// persistent accumulator is 64 VGPR/thread (R3's 128-VGPR acc caused ~300 MB
// of scratch spill traffic = the whole kernel time).
// LDS layout (dynamic):
//   sorted16 u16[8192]  (t<<9|src, sorted by dst; dst implied by cs segments)
//   cs i32[513] | wsc f32[512] | wint i32[512] | b1sh/b2sh f32[128]
//   S1 scratch 69632: CSR aux -> Sint[256][68] -> h1sh[256][136] -> A u8[128][264] -> red
//   h2l bf16 65536: H2 of current src-half in agg2-B-fragment layout
#define OFF_SORT 0
#define OFF_CS   16384
#define OFF_WSC  18440
#define OFF_WINT 20488
#define OFF_B1   22536
#define OFF_B2   23048
#define OFF_S1   23568
#define OFF_H2L  93200
#define MEGA_LDS 158736

__global__ __launch_bounds__(512,1) void k_half(
      const int* __restrict__ src, const int* __restrict__ dst,
      const int* __restrict__ ntype, const float* __restrict__ b1,
      const float* __restrict__ b2, const unsigned short* __restrict__ EW1T,
      const unsigned short* __restrict__ W2F, float* __restrict__ out){
  extern __shared__ char smem[];
  unsigned short* sorted16 = (unsigned short*)(smem + OFF_SORT);
  int*   cs   = (int*)(smem + OFF_CS);
  float* wsc  = (float*)(smem + OFF_WSC);
  int*   wint = (int*)(smem + OFF_WINT);
  float* b1sh = (float*)(smem + OFF_B1);
  float* b2sh = (float*)(smem + OFF_B2);
  char*  S1   = smem + OFF_S1;
  unsigned short* h2l = (unsigned short*)(smem + OFF_H2L);
  // phase-1 aliases (CSR aux)
  int* hist   = (int*)S1;                       // [512]
  int* cursor = hist + 512;                     // [512]
  int* co     = cursor + 512;                   // [512]
  unsigned short* ntype_sh = (unsigned short*)(co + 512); // [512]
  // later aliases
  int* Sint = (int*)S1;                         // [256][68]
  unsigned short* h1sh = (unsigned short*)S1;   // [256][136]
  unsigned char* A = (unsigned char*)S1;        // [128][264]
  unsigned int* A32 = (unsigned int*)S1;
  float* red = (float*)S1;                      // [8][64]

  const int bid = blockIdx.x, tid = threadIdx.x;
  const int b     = ((bid>>4)<<3) | (bid&7);    // graph (XCD-aligned swizzle)
  const int dhalf = (bid>>3)&1;                 // this block's dst half
  const int eb = b*EPG, nb = b*NPG;

  // ================= phase 1: CSR (all in LDS, no global writes) ===========
  hist[tid]=0; co[tid]=0; ntype_sh[tid]=(unsigned short)ntype[nb+tid];
  if (tid<128){ b1sh[tid]=b1[tid]; b2sh[tid]=b2[tid]; }
  __syncthreads();
  int4 d4[4], s4[4];
  {
    const int4* dv = (const int4*)(dst+eb);
    const int4* sv = (const int4*)(src+eb);
    #pragma unroll
    for (int j=0;j<4;j++){
      d4[j]=dv[tid + j*512];
      s4[j]=sv[tid + j*512];
      atomicAdd(&hist[d4[j].x&(NPG-1)],1); atomicAdd(&hist[d4[j].y&(NPG-1)],1);
      atomicAdd(&hist[d4[j].z&(NPG-1)],1); atomicAdd(&hist[d4[j].w&(NPG-1)],1);
      atomicAdd(&co[s4[j].x&(NPG-1)],1);   atomicAdd(&co[s4[j].y&(NPG-1)],1);
      atomicAdd(&co[s4[j].z&(NPG-1)],1);   atomicAdd(&co[s4[j].w&(NPG-1)],1);
    }
  }
  __syncthreads();
  if (tid<64){
    int carry=0;
    #pragma unroll
    for (int c=0;c<8;c++){
      int sc=hist[64*c+tid];
      #pragma unroll
      for (int off=1;off<64;off<<=1){ int y=__shfl_up(sc,off); if (tid>=off) sc+=y; }
      cs[64*c+tid+1]=carry+sc;
      carry+=__shfl(sc,63);
    }
    if (tid==0) cs[0]=0;
  }
  __syncthreads();
  cursor[tid]=cs[tid];
  __syncthreads();
  #pragma unroll
  for (int j=0;j<4;j++){
    int dl, s, pos;
    dl=d4[j].x&(NPG-1); s=s4[j].x&(NPG-1);
    pos=atomicAdd(&cursor[dl],1);
    sorted16[pos]=(unsigned short)(((unsigned int)ntype_sh[s]<<9)|(unsigned int)s);
    dl=d4[j].y&(NPG-1); s=s4[j].y&(NPG-1);
    pos=atomicAdd(&cursor[dl],1);
    sorted16[pos]=(unsigned short)(((unsigned int)ntype_sh[s]<<9)|(unsigned int)s);
    dl=d4[j].z&(NPG-1); s=s4[j].z&(NPG-1);
    pos=atomicAdd(&cursor[dl],1);
    sorted16[pos]=(unsigned short)(((unsigned int)ntype_sh[s]<<9)|(unsigned int)s);
    dl=d4[j].w&(NPG-1); s=s4[j].w&(NPG-1);
    pos=atomicAdd(&cursor[dl],1);
    sorted16[pos]=(unsigned short)(((unsigned int)ntype_sh[s]<<9)|(unsigned int)s);
  }
  {                                             // out-degree isqrt (co valid)
    int a=co[tid]; if(a<1)a=1;
    const float w = rsqrtf((float)a);
    wsc[tid]=w; wint[tid]=(int)(w*1048576.f);   // 2^20 fixed point
  }
  __syncthreads();                              // CSR done; S1 free

  const int wave=tid>>6, lane=tid&63, l16=lane&15, quad=lane>>4;
  const int mg2=wave>>1, ng2=wave&1;            // agg2 map: A-unpack 2x only
  f32x4 acc[2][2][4];                           // [dt][rt][ct] = 64 VGPR
  #pragma unroll
  for (int dt2=0;dt2<2;dt2++)
    #pragma unroll
    for (int rt=0;rt<2;rt++)
      #pragma unroll
      for (int ct=0;ct<4;ct++) acc[dt2][rt][ct]=(f32x4){0.f,0.f,0.f,0.f};

  #pragma unroll 1
  for (int h=0; h<2; ++h){                      // src-half / h1-row-half
    const int v0 = h*256;
    // ---- agg1 scatter: Sint[r][t] += wint[src] ----
    for (int i=tid; i<(256*68)/4; i+=512) ((f32x4*)Sint)[i]=(f32x4){0.f,0.f,0.f,0.f};
    __syncthreads();
    {
      const int r = tid>>1, p = tid&1;          // 2 threads per dst row
      const int e1 = cs[v0+r+1];
      for (int i=cs[v0+r]+p; i<e1; i+=2){
        const unsigned int e = sorted16[i];
        atomicAdd(&Sint[r*68 + (int)(e>>9)], wint[e&511]);
      }
    }
    __syncthreads();
    // ---- pass 1: MFMA(S_hi/lo @ EW1T) ----
    f32x4 acc1[2][8];
    #pragma unroll
    for (int rt=0;rt<2;rt++)
      #pragma unroll
      for (int nt=0;nt<8;nt++) acc1[rt][nt]=(f32x4){0.f,0.f,0.f,0.f};
    #pragma unroll
    for (int kh=0; kh<2; ++kh){
      s16x8 fh[2], fl[2];
      #pragma unroll
      for (int rt=0;rt<2;rt++){
        const int m = (wave*2+rt)*16 + l16;
        const int* sp = &Sint[m*68 + kh*32 + quad*8];
        union { s16x8 v; unsigned short u[8]; } hv, lv;
        #pragma unroll
        for (int j=0;j<8;j++){
          const float f = (float)sp[j] * (1.f/1048576.f);   // exact exp shift
          const unsigned short hi = f2bf(f);
          hv.u[j]=hi; lv.u[j]=f2bf(f - bf2f(hi));
        }
        fh[rt]=hv.v; fl[rt]=lv.v;
      }
      const int kc = kh*32 + quad*8;
      #pragma unroll
      for (int nt=0;nt<8;nt++){                 // one B-frag feeds hi AND lo
        s16x8 bfr=__builtin_bit_cast(s16x8,
            *(const uint4*)(EW1T + (size_t)(nt*16+l16)*64 + kc));
        acc1[0][nt]=__builtin_amdgcn_mfma_f32_16x16x32_bf16(fh[0],bfr,acc1[0][nt],0,0,0);
        acc1[1][nt]=__builtin_amdgcn_mfma_f32_16x16x32_bf16(fh[1],bfr,acc1[1][nt],0,0,0);
        acc1[0][nt]=__builtin_amdgcn_mfma_f32_16x16x32_bf16(fl[0],bfr,acc1[0][nt],0,0,0);
        acc1[1][nt]=__builtin_amdgcn_mfma_f32_16x16x32_bf16(fl[1],bfr,acc1[1][nt],0,0,0);
      }
    }
    // ---- epilogue 1: h1 = relu(agg*isq+b1)*osc -> h1sh ----
    float isq[2][4], os[2][4];
    #pragma unroll
    for (int rt=0;rt<2;rt++){
      const int mloc = (wave*2+rt)*16 + quad*4;
      #pragma unroll
      for (int r=0;r<4;r++){
        int d = cs[v0+mloc+r+1]-cs[v0+mloc+r]; if (d<1) d=1;
        isq[rt][r]=rsqrtf((float)d);
        os[rt][r]=wsc[v0+mloc+r];
      }
    }
    __syncthreads();                            // all Sint reads done
    #pragma unroll
    for (int rt=0;rt<2;rt++){
      const int mloc = (wave*2+rt)*16 + quad*4;
      #pragma unroll
      for (int nt=0;nt<8;nt++){
        const int col = nt*16+l16;
        const float bb = b1sh[col];
        #pragma unroll
        for (int r=0;r<4;r++){
          const float v = fmaxf(acc1[rt][nt][r]*isq[rt][r]+bb,0.f)*os[rt][r];
          h1sh[(mloc+r)*136 + col] = f2bf(v);
        }
      }
    }
    __syncthreads();
    // ---- pass 2: H2 = h1 @ W2 -> h2l (LDS, B-fragment layout) ----
    f32x4 acc2[2][8];
    #pragma unroll
    for (int rt=0;rt<2;rt++)
      #pragma unroll
      for (int nt=0;nt<8;nt++) acc2[rt][nt]=(f32x4){0.f,0.f,0.f,0.f};
    #pragma unroll
    for (int ks=0; ks<4; ++ks){
      s16x8 a2[2];
      #pragma unroll
      for (int rt=0;rt<2;rt++){
        const int m = (wave*2+rt)*16 + l16;
        a2[rt]=__builtin_bit_cast(s16x8,
            *(const uint4*)(h1sh + m*136 + ks*32 + quad*8));
      }
      #pragma unroll
      for (int nt=0;nt<8;nt++){
        s16x8 bfr=__builtin_bit_cast(s16x8,
            *(const uint4*)(W2F + (size_t)(((ks*8+nt)*64)+lane)*8));
        #pragma unroll
        for (int rt=0;rt<2;rt++)
          acc2[rt][nt]=__builtin_amdgcn_mfma_f32_16x16x32_bf16(a2[rt],bfr,acc2[rt][nt],0,0,0);
      }
    }
    // epilogue 2: write h2l in B-frag order (local ks2 = W>>1, K=256)
    #pragma unroll
    for (int rt=0;rt<2;rt++){
      const int W = wave*2+rt;
      const int ks2 = W>>1;
      const int q2  = ((W&1)<<1) | (quad>>1);
      const int j0  = (quad&1)*4;
      #pragma unroll
      for (int nt=0;nt<8;nt++){
        ushort4 st;
        st.x=f2bf(acc2[rt][nt][0]); st.y=f2bf(acc2[rt][nt][1]);
        st.z=f2bf(acc2[rt][nt][2]); st.w=f2bf(acc2[rt][nt][3]);
        *(ushort4*)(h2l + (size_t)(((ks2*8+nt)*64 + q2*16 + l16)*8 + j0)) = st;
      }
    }
    __syncthreads();                            // h1sh reads + h2l writes done
    // ---- agg2: counts(dst-tile, src-half) @ h2l -> acc (this dst-half) ----
    #pragma unroll 1
    for (int dt=0; dt<2; ++dt){
      const int r0 = dhalf*256 + dt*128;
      for (int i=tid; i<(128*264)/16; i+=512) ((uint4*)A)[i]=(uint4){0u,0u,0u,0u};
      __syncthreads();
      {
        const int r = tid>>2, p = tid&3;        // 4 threads per dst row
        const int e1 = cs[r0+r+1];
        for (int i=cs[r0+r]+p; i<e1; i+=4){
          const int s = (int)(sorted16[i] & 511u);
          if ((s>>8)==h)
            atomicAdd(&A32[r*66 + ((s&255)>>2)], 1u<<((s&3)*8));
        }
      }
      __syncthreads();
      const unsigned char* Ab0 = A + ((mg2*2+0)*16 + l16)*264 + quad*8;
      const unsigned char* Ab1 = A + ((mg2*2+1)*16 + l16)*264 + quad*8;
      #pragma unroll
      for (int ks=0; ks<8; ++ks){
        uint4 bq[4];
        #pragma unroll
        for (int ct=0;ct<4;ct++)
          bq[ct] = *(const uint4*)(h2l + (size_t)(((ks*8 + ng2*4+ct)*64 + lane)*8));
        #pragma unroll
        for (int rt=0;rt<2;rt++){
          const uint2 aw = *(const uint2*)((rt ? Ab1 : Ab0) + ks*32);
          union { s16x8 v; unsigned int u[4]; } pk;
          {
            const float g0=(float)( aw.x       &0xffu);
            const float g1=(float)((aw.x>> 8u) &0xffu);
            const float g2=(float)((aw.x>>16u) &0xffu);
            const float g3=(float)( aw.x>>24u        );
            pk.u[0]=__builtin_amdgcn_perm(__builtin_bit_cast(unsigned int,g1),
                                          __builtin_bit_cast(unsigned int,g0),0x07060302u);
            pk.u[1]=__builtin_amdgcn_perm(__builtin_bit_cast(unsigned int,g3),
                                          __builtin_bit_cast(unsigned int,g2),0x07060302u);
          }
          {
            const float g0=(float)( aw.y       &0xffu);
            const float g1=(float)((aw.y>> 8u) &0xffu);
            const float g2=(float)((aw.y>>16u) &0xffu);
            const float g3=(float)( aw.y>>24u        );
            pk.u[2]=__builtin_amdgcn_perm(__builtin_bit_cast(unsigned int,g1),
                                          __builtin_bit_cast(unsigned int,g0),0x07060302u);
            pk.u[3]=__builtin_amdgcn_perm(__builtin_bit_cast(unsigned int,g3),
                                          __builtin_bit_cast(unsigned int,g2),0x07060302u);
          }
          #pragma unroll
          for (int ct=0;ct<4;ct++)
            acc[dt][rt][ct]=__builtin_amdgcn_mfma_f32_16x16x32_bf16(pk.v,
                __builtin_bit_cast(s16x8, bq[ct]), acc[dt][rt][ct],0,0,0);
        }
      }
      __syncthreads();                          // A reads done before next zero
    }
  } // h

  // ========= final epilogue: relu + column partial-sum -> atomicAdd ========
  float p[4]; p[0]=0.f; p[1]=0.f; p[2]=0.f; p[3]=0.f;
  #pragma unroll
  for (int dt=0; dt<2; ++dt){
    #pragma unroll
    for (int rt=0;rt<2;rt++){
      const int mrow = dhalf*256 + dt*128 + (mg2*2+rt)*16 + quad*4;
      float isq2[4];
      #pragma unroll
      for (int r=0;r<4;r++){
        int d=cs[mrow+r+1]-cs[mrow+r]; if (d<1) d=1;
        isq2[r]=rsqrtf((float)d);
      }
      #pragma unroll
      for (int ct=0;ct<4;ct++){
        const int col=(ng2*4+ct)*16 + l16;
        const float bb = b2sh[col];
        #pragma unroll
        for (int r=0;r<4;r++)
          p[ct] += fmaxf(acc[dt][rt][ct][r]*isq2[r]+bb,0.f);
      }
    }
  }
  #pragma unroll
  for (int ct=0;ct<4;ct++){
    p[ct] += __shfl_xor(p[ct],16);              // reduce rows across quads
    p[ct] += __shfl_xor(p[ct],32);
  }
  __syncthreads();                              // all A reads done; red aliases
  if (quad==0){
    #pragma unroll
    for (int ct=0;ct<4;ct++) red[wave*64 + ct*16 + l16] = p[ct];
  }
  __syncthreads();
  if (tid<128){
    const int col=tid, ngc=col>>6, c6=col&63;
    float s=0.f;
    #pragma unroll
    for (int k=0;k<4;k++) s += red[(2*k+ngc)*64 + c6];
    atomicAdd(out + (size_t)b*128 + col, s*(1.f/512.f));
  }
}

extern "C" void kernel_launch(void* const* d_in, const int* in_sizes, int n_in,
                              void* d_out, int out_size, void* d_ws, size_t ws_size,
                              hipStream_t stream){
  const int* node_feat = (const int*)d_in[0];
  const int* src = (const int*)d_in[1];
  const int* dst = (const int*)d_in[2];
  const float* emb = (const float*)d_in[3];
  const float* W1  = (const float*)d_in[4];
  const float* b1  = (const float*)d_in[5];
  const float* W2  = (const float*)d_in[6];
  const float* b2  = (const float*)d_in[7];

  char* ws = (char*)d_ws;
  unsigned short* EW1T = (unsigned short*)(ws);            // 16384 B
  unsigned short* W2F  = (unsigned short*)(ws + 16384);    // 32768 B

  (void)hipFuncSetAttribute(reinterpret_cast<const void*>(&k_half),
        hipFuncAttributeMaxDynamicSharedMemorySize, MEGA_LDS);

  k_prep<<<GRAPHS,128,0,stream>>>(emb,W1,W2,EW1T,W2F,(float*)d_out);
  k_half<<<GRAPHS*2,512,MEGA_LDS,stream>>>(src,dst,node_feat,b1,b2,EW1T,W2F,
        (float*)d_out);
}

// Round 5
// 170.372 us; speedup vs baseline: 2.4241x; 2.4241x over previous
//
#include <hip/hip_runtime.h>
#include <stdint.h>

#define GRAPHS 256
#define NPG    512
#define EPG    8192

typedef __attribute__((ext_vector_type(8))) short s16x8;
typedef __attribute__((ext_vector_type(4))) float f32x4;

__device__ __forceinline__ float bf2f(unsigned short u){
  union { unsigned int i; float f; } c; c.i = ((unsigned int)u)<<16; return c.f;
}
__device__ __forceinline__ unsigned short f2bf(float f){
  union { float f; unsigned int i; } c; c.f = f;
  unsigned int r = c.i + 0x7fffu + ((c.i>>16)&1u);   // RNE (software; do NOT
  return (unsigned short)(r>>16);                    // use v_cvt_pk_bf16_f32)
}

// ------- tiny prep: EW1T + W2F (bit-identical to passing R2) ---------------
__global__ __launch_bounds__(128) void k_prep(const float* __restrict__ emb,
      const float* __restrict__ W1, const float* __restrict__ W2,
      unsigned short* __restrict__ EW1T, unsigned short* __restrict__ W2F){
  const int b = blockIdx.x, tid = threadIdx.x;
  if (tid < 32){                                 // EW1T: serial f32 dot
    const int gid = b*32 + tid;
    const int t = gid>>7, c = gid&127;
    float acc=0.f;
    #pragma unroll 4
    for (int k=0;k<128;k++) acc += emb[t*128+k]*W1[k*128+c];
    EW1T[c*64+t]=f2bf(acc);
  } else if (tid >= 64){                         // W2F fragment order
    const int i = b*64 + (tid-64);
    const int ks = i>>12, nt=(i>>9)&7, ln=(i>>3)&63, j=i&7;
    const int k = ks*32 + (ln>>4)*8 + j;
    const int n = nt*16 + (ln&15);
    W2F[i] = f2bf(W2[k*128+n]);
  }
}

// ---------------- fused kernel: 1 block = 1 graph ---------------------------
// Key restructure vs R3/R4 (which spilled ~300-875 MB of scratch): use
// counts@(h1@W2) == (counts@h1)@W2.  Keep h1 (BOTH halves) in LDS in
// MFMA-B-fragment order; per 16-dst-row tile: scatter u8 counts -> MFMA
// G=counts@h1 -> scale isq -> bf16 hi/lo -> MFMA H3=Gb@W2F -> relu+colsum
// into ONE scalar pp/thread.  No persistent register arrays anywhere
// (rule #20: all reg arrays indexed by fully-unrolled loop vars only).
// LDS (163344 B, 1 block/CU):
//   sorted16 u16[8192] | cs[513] | wsc[512] | wint[512] | b1sh | b2sh
//   h1F bf16 131072: h1*osc, frag order [ks16][nt8][lane64][j8]
//   A/Gb region 8704: A u8[16][520] -> Gb_hi/lo bf16[16][136] -> red f32[128]
//   Sint i32[256][68] @89104 (phases 2-3 only; overlaps h1F-half1 home + A:
//   half1 is written from regs AFTER all Sint reads complete)
#define OFF_SORT 0
#define OFF_CS   16384
#define OFF_WSC  18440
#define OFF_WINT 20488
#define OFF_B1   22536
#define OFF_B2   23048
#define OFF_H1F  23568
#define OFF_AG   154640
#define OFF_SINT 89104
#define OFF_CSRA 23568
#define FUSED_LDS 163344

__global__ __launch_bounds__(512,2) void k_fused(
      const int* __restrict__ src, const int* __restrict__ dst,
      const int* __restrict__ ntype, const float* __restrict__ b1,
      const float* __restrict__ b2, const unsigned short* __restrict__ EW1T,
      const unsigned short* __restrict__ W2F, float* __restrict__ out){
  extern __shared__ char smem[];
  unsigned short* sorted16 = (unsigned short*)(smem + OFF_SORT);
  int*   cs   = (int*)(smem + OFF_CS);
  float* wsc  = (float*)(smem + OFF_WSC);
  int*   wint = (int*)(smem + OFF_WINT);
  float* b1sh = (float*)(smem + OFF_B1);
  float* b2sh = (float*)(smem + OFF_B2);
  unsigned short* h1F = (unsigned short*)(smem + OFF_H1F);
  int*   Sint = (int*)(smem + OFF_SINT);        // [256][68], phases 2-3
  unsigned char* A  = (unsigned char*)(smem + OFF_AG);   // [16][520]
  unsigned int*  A32 = (unsigned int*)(smem + OFF_AG);
  unsigned short* gbh = (unsigned short*)(smem + OFF_AG);        // [16][136]
  unsigned short* gbl = (unsigned short*)(smem + OFF_AG + 4352); // [16][136]
  float* red = (float*)(smem + OFF_AG);         // [128] final alias
  // CSR-phase aliases (over h1F region, dead then)
  int* hist   = (int*)(smem + OFF_CSRA);        // [512]
  int* cursor = hist + 512;                     // [512]
  int* co     = cursor + 512;                   // [512]
  unsigned short* ntype_sh = (unsigned short*)(co + 512); // [512]

  const int b = blockIdx.x, tid = threadIdx.x;
  const int eb = b*EPG, nb = b*NPG;

  // ================= phase 1: CSR (all in LDS) =============================
  hist[tid]=0; co[tid]=0; ntype_sh[tid]=(unsigned short)ntype[nb+tid];
  if (tid<128){ b1sh[tid]=b1[tid]; b2sh[tid]=b2[tid]; }
  __syncthreads();
  int4 d4[4], s4[4];
  {
    const int4* dv = (const int4*)(dst+eb);
    const int4* sv = (const int4*)(src+eb);
    #pragma unroll
    for (int j=0;j<4;j++){
      d4[j]=dv[tid + j*512];
      s4[j]=sv[tid + j*512];
      atomicAdd(&hist[d4[j].x&(NPG-1)],1); atomicAdd(&hist[d4[j].y&(NPG-1)],1);
      atomicAdd(&hist[d4[j].z&(NPG-1)],1); atomicAdd(&hist[d4[j].w&(NPG-1)],1);
      atomicAdd(&co[s4[j].x&(NPG-1)],1);   atomicAdd(&co[s4[j].y&(NPG-1)],1);
      atomicAdd(&co[s4[j].z&(NPG-1)],1);   atomicAdd(&co[s4[j].w&(NPG-1)],1);
    }
  }
  __syncthreads();
  if (tid<64){
    int carry=0;
    #pragma unroll
    for (int c=0;c<8;c++){
      int sc=hist[64*c+tid];
      #pragma unroll
      for (int off=1;off<64;off<<=1){ int y=__shfl_up(sc,off); if (tid>=off) sc+=y; }
      cs[64*c+tid+1]=carry+sc;
      carry+=__shfl(sc,63);
    }
    if (tid==0) cs[0]=0;
  }
  __syncthreads();
  cursor[tid]=cs[tid];
  __syncthreads();
  #pragma unroll
  for (int j=0;j<4;j++){
    int dl, s, pos;
    dl=d4[j].x&(NPG-1); s=s4[j].x&(NPG-1);
    pos=atomicAdd(&cursor[dl],1);
    sorted16[pos]=(unsigned short)(((unsigned int)ntype_sh[s]<<9)|(unsigned int)s);
    dl=d4[j].y&(NPG-1); s=s4[j].y&(NPG-1);
    pos=atomicAdd(&cursor[dl],1);
    sorted16[pos]=(unsigned short)(((unsigned int)ntype_sh[s]<<9)|(unsigned int)s);
    dl=d4[j].z&(NPG-1); s=s4[j].z&(NPG-1);
    pos=atomicAdd(&cursor[dl],1);
    sorted16[pos]=(unsigned short)(((unsigned int)ntype_sh[s]<<9)|(unsigned int)s);
    dl=d4[j].w&(NPG-1); s=s4[j].w&(NPG-1);
    pos=atomicAdd(&cursor[dl],1);
    sorted16[pos]=(unsigned short)(((unsigned int)ntype_sh[s]<<9)|(unsigned int)s);
  }
  {                                             // out-degree isqrt
    int a=co[tid]; if(a<1)a=1;
    const float w = rsqrtf((float)a);
    wsc[tid]=w; wint[tid]=(int)(w*1048576.f);   // 2^20 fixed point
  }
  __syncthreads();                              // CSR done

  const int wave=tid>>6, lane=tid&63, l16=lane&15, quad=lane>>4;

  // ============ phases 2-3: layer-1 -> h1F (frag order), per src-half ======
  #pragma unroll 1
  for (int h=0; h<2; ++h){
    const int v0 = h*256;
    for (int i=tid; i<(256*68)/4; i+=512) ((f32x4*)Sint)[i]=(f32x4){0.f,0.f,0.f,0.f};
    __syncthreads();
    {                                           // edge scatter (2 thr/row)
      const int r = tid>>1, p = tid&1;
      const int e1 = cs[v0+r+1];
      for (int i=cs[v0+r]+p; i<e1; i+=2){
        const unsigned int e = sorted16[i];
        atomicAdd(&Sint[r*68 + (int)(e>>9)], wint[e&511]);
      }
    }
    __syncthreads();
    f32x4 acc1[2][8];
    #pragma unroll
    for (int rt=0;rt<2;rt++)
      #pragma unroll
      for (int nt=0;nt<8;nt++) acc1[rt][nt]=(f32x4){0.f,0.f,0.f,0.f};
    #pragma unroll
    for (int kh=0; kh<2; ++kh){
      s16x8 fh[2], fl[2];
      #pragma unroll
      for (int rt=0;rt<2;rt++){
        const int m = (wave*2+rt)*16 + l16;
        const int* sp = &Sint[m*68 + kh*32 + quad*8];
        union { s16x8 v; unsigned short u[8]; } hv, lv;
        #pragma unroll
        for (int j=0;j<8;j++){
          const float f = (float)sp[j] * (1.f/1048576.f);   // exact exp shift
          const unsigned short hi = f2bf(f);
          hv.u[j]=hi; lv.u[j]=f2bf(f - bf2f(hi));
        }
        fh[rt]=hv.v; fl[rt]=lv.v;
      }
      const int kc = kh*32 + quad*8;
      #pragma unroll
      for (int nt=0;nt<8;nt++){                 // one B-frag feeds hi AND lo
        s16x8 bfr=__builtin_bit_cast(s16x8,
            *(const uint4*)(EW1T + (size_t)(nt*16+l16)*64 + kc));
        acc1[0][nt]=__builtin_amdgcn_mfma_f32_16x16x32_bf16(fh[0],bfr,acc1[0][nt],0,0,0);
        acc1[1][nt]=__builtin_amdgcn_mfma_f32_16x16x32_bf16(fh[1],bfr,acc1[1][nt],0,0,0);
        acc1[0][nt]=__builtin_amdgcn_mfma_f32_16x16x32_bf16(fl[0],bfr,acc1[0][nt],0,0,0);
        acc1[1][nt]=__builtin_amdgcn_mfma_f32_16x16x32_bf16(fl[1],bfr,acc1[1][nt],0,0,0);
      }
    }
    float isq[2][4], os[2][4];
    #pragma unroll
    for (int rt=0;rt<2;rt++){
      const int mloc = (wave*2+rt)*16 + quad*4;
      #pragma unroll
      for (int r=0;r<4;r++){
        int d = cs[v0+mloc+r+1]-cs[v0+mloc+r]; if (d<1) d=1;
        isq[rt][r]=rsqrtf((float)d);
        os[rt][r]=wsc[v0+mloc+r];
      }
    }
    __syncthreads();       // ALL Sint reads done (h1F-half1 overlaps Sint!)
    // epilogue 1: h1 = relu(agg*isq+b1)*osc -> h1F in B-frag order
    #pragma unroll
    for (int rt=0;rt<2;rt++){
      const int ksg = h*8 + wave;               // k = v0+mloc+r -> ks tile
      const int kq  = rt*2 + (quad>>1);
      const int j0  = (quad&1)*4;
      #pragma unroll
      for (int nt=0;nt<8;nt++){
        const int col = nt*16+l16;
        const float bb1 = b1sh[col];
        ushort4 st;
        st.x = f2bf(fmaxf(acc1[rt][nt][0]*isq[rt][0]+bb1,0.f)*os[rt][0]);
        st.y = f2bf(fmaxf(acc1[rt][nt][1]*isq[rt][1]+bb1,0.f)*os[rt][1]);
        st.z = f2bf(fmaxf(acc1[rt][nt][2]*isq[rt][2]+bb1,0.f)*os[rt][2]);
        st.w = f2bf(fmaxf(acc1[rt][nt][3]*isq[rt][3]+bb1,0.f)*os[rt][3]);
        *(ushort4*)(h1F + ((((ksg*8+nt)*64) + kq*16 + l16)*8 + j0)) = st;
      }
    }
    __syncthreads();
  } // h

  // ============ phase 4: layer-2 per 16-row dst tile =======================
  // hoist this wave's B-frags: h1F (nt=wave) and W2F (nt=wave) to registers
  s16x8 bh[16];
  #pragma unroll
  for (int ks=0;ks<16;ks++)
    bh[ks] = __builtin_bit_cast(s16x8,
        *(const uint4*)(h1F + (((ks*8+wave)*64 + lane)*8)));
  uint4 w2q[4];
  #pragma unroll
  for (int ks2=0;ks2<4;ks2++)
    w2q[ks2] = *(const uint4*)(W2F + (size_t)(((ks2*8+wave)*64)+lane)*8);
  const float bb2 = b2sh[wave*16+l16];
  float pp = 0.f;

  #pragma unroll 1
  for (int dt=0; dt<32; ++dt){
    const int r0 = dt*16;
    for (int i=tid; i<520; i+=512) ((uint4*)A)[i]=(uint4){0u,0u,0u,0u};
    __syncthreads();
    {                                           // count scatter (32 thr/row)
      const int r = tid>>5, p = tid&31;
      const int e1 = cs[r0+r+1];
      for (int i=cs[r0+r]+p; i<e1; i+=32){
        const int s = (int)(sorted16[i] & 511u);
        atomicAdd(&A32[r*130 + (s>>2)], 1u<<((s&3)*8));
      }
    }
    __syncthreads();
    // G = counts @ h1F   (M=16, N=128 -> wave owns nt=wave, K=512)
    f32x4 g=(f32x4){0.f,0.f,0.f,0.f};
    #pragma unroll
    for (int ks=0;ks<16;ks++){
      const uint2 aw = *(const uint2*)(A + l16*520 + ks*32 + quad*8);
      union { s16x8 v; unsigned int u[4]; } pk;
      {
        const float g0=(float)( aw.x       &0xffu);
        const float g1=(float)((aw.x>> 8u) &0xffu);
        const float g2=(float)((aw.x>>16u) &0xffu);
        const float g3=(float)( aw.x>>24u        );
        pk.u[0]=__builtin_amdgcn_perm(__builtin_bit_cast(unsigned int,g1),
                                      __builtin_bit_cast(unsigned int,g0),0x07060302u);
        pk.u[1]=__builtin_amdgcn_perm(__builtin_bit_cast(unsigned int,g3),
                                      __builtin_bit_cast(unsigned int,g2),0x07060302u);
      }
      {
        const float g0=(float)( aw.y       &0xffu);
        const float g1=(float)((aw.y>> 8u) &0xffu);
        const float g2=(float)((aw.y>>16u) &0xffu);
        const float g3=(float)( aw.y>>24u        );
        pk.u[2]=__builtin_amdgcn_perm(__builtin_bit_cast(unsigned int,g1),
                                      __builtin_bit_cast(unsigned int,g0),0x07060302u);
        pk.u[3]=__builtin_amdgcn_perm(__builtin_bit_cast(unsigned int,g3),
                                      __builtin_bit_cast(unsigned int,g2),0x07060302u);
      }
      g=__builtin_amdgcn_mfma_f32_16x16x32_bf16(pk.v, bh[ks], g,0,0,0);
    }
    __syncthreads();                            // A reads done (Gb aliases A)
    // Gb = bf16_hi/lo( G * isq )  rows quad*4+ri, col wave*16+l16
    #pragma unroll
    for (int ri=0;ri<4;ri++){
      const int row = quad*4+ri;
      int d = cs[r0+row+1]-cs[r0+row]; if (d<1) d=1;
      const float gs = g[ri]*rsqrtf((float)d);
      const unsigned short hi = f2bf(gs);
      gbh[row*136 + wave*16+l16] = hi;
      gbl[row*136 + wave*16+l16] = f2bf(gs - bf2f(hi));
    }
    __syncthreads();                            // Gb ready (A-frags span cols)
    // H3 = Gb @ W2  (M=16, N=128 -> nt=wave, K=128, hi+lo)
    f32x4 a2=(f32x4){0.f,0.f,0.f,0.f};
    #pragma unroll
    for (int ks2=0;ks2<4;ks2++){
      const s16x8 ah = __builtin_bit_cast(s16x8,
          *(const uint4*)(gbh + l16*136 + ks2*32 + quad*8));
      a2=__builtin_amdgcn_mfma_f32_16x16x32_bf16(ah,
          __builtin_bit_cast(s16x8,w2q[ks2]), a2,0,0,0);
      const s16x8 al = __builtin_bit_cast(s16x8,
          *(const uint4*)(gbl + l16*136 + ks2*32 + quad*8));
      a2=__builtin_amdgcn_mfma_f32_16x16x32_bf16(al,
          __builtin_bit_cast(s16x8,w2q[ks2]), a2,0,0,0);
    }
    #pragma unroll
    for (int ri=0;ri<4;ri++) pp += fmaxf(a2[ri]+bb2, 0.f);
    __syncthreads();                            // Gb reads done (next zeroes A)
  }

  // ============ final: column sums -> out (no atomics) =====================
  pp += __shfl_xor(pp,16);                      // sum the 4 quads' row groups
  pp += __shfl_xor(pp,32);
  if (quad==0) red[wave*16+l16] = pp;
  __syncthreads();
  if (tid<128) out[(size_t)b*128 + tid] = red[tid]*(1.f/512.f);
}

extern "C" void kernel_launch(void* const* d_in, const int* in_sizes, int n_in,
                              void* d_out, int out_size, void* d_ws, size_t ws_size,
                              hipStream_t stream){
  const int* node_feat = (const int*)d_in[0];
  const int* src = (const int*)d_in[1];
  const int* dst = (const int*)d_in[2];
  const float* emb = (const float*)d_in[3];
  const float* W1  = (const float*)d_in[4];
  const float* b1  = (const float*)d_in[5];
  const float* W2  = (const float*)d_in[6];
  const float* b2  = (const float*)d_in[7];

  char* ws = (char*)d_ws;
  unsigned short* EW1T = (unsigned short*)(ws);            // 16384 B
  unsigned short* W2F  = (unsigned short*)(ws + 16384);    // 32768 B

  (void)hipFuncSetAttribute(reinterpret_cast<const void*>(&k_fused),
        hipFuncAttributeMaxDynamicSharedMemorySize, FUSED_LDS);

  k_prep<<<GRAPHS,128,0,stream>>>(emb,W1,W2,EW1T,W2F);
  k_fused<<<GRAPHS,512,FUSED_LDS,stream>>>(src,dst,node_feat,b1,b2,EW1T,W2F,
        (float*)d_out);
}

// Round 6
// 166.447 us; speedup vs baseline: 2.4813x; 1.0236x over previous
//
#include <hip/hip_runtime.h>
#include <stdint.h>

#define GRAPHS 256
#define NPG    512
#define EPG    8192

typedef __attribute__((ext_vector_type(8))) short s16x8;
typedef __attribute__((ext_vector_type(4))) float f32x4;

__device__ __forceinline__ float bf2f(unsigned short u){
  union { unsigned int i; float f; } c; c.i = ((unsigned int)u)<<16; return c.f;
}
__device__ __forceinline__ unsigned short f2bf(float f){
  union { float f; unsigned int i; } c; c.f = f;
  unsigned int r = c.i + 0x7fffu + ((c.i>>16)&1u);   // RNE (software; do NOT
  return (unsigned short)(r>>16);                    // use v_cvt_pk_bf16_f32)
}

// ------- tiny prep: EW1T + W2F (bit-identical to passing R2) ---------------
__global__ __launch_bounds__(128) void k_prep(const float* __restrict__ emb,
      const float* __restrict__ W1, const float* __restrict__ W2,
      unsigned short* __restrict__ EW1T, unsigned short* __restrict__ W2F){
  const int b = blockIdx.x, tid = threadIdx.x;
  if (tid < 32){                                 // EW1T: serial f32 dot
    const int gid = b*32 + tid;
    const int t = gid>>7, c = gid&127;
    float acc=0.f;
    #pragma unroll 4
    for (int k=0;k<128;k++) acc += emb[t*128+k]*W1[k*128+c];
    EW1T[c*64+t]=f2bf(acc);
  } else if (tid >= 64){                         // W2F fragment order
    const int i = b*64 + (tid-64);
    const int ks = i>>12, nt=(i>>9)&7, ln=(i>>3)&63, j=i&7;
    const int k = ks*32 + (ln>>4)*8 + j;
    const int n = nt*16 + (ln&15);
    W2F[i] = f2bf(W2[k*128+n]);
  }
}

// ---------------- fused kernel: 1 block = 1 graph ---------------------------
// Phases 1-3 identical to R5 (verified).  Phase 4 rebuilt: after the bh[16]
// register hoist, h1F's 131 KB LDS is DEAD -> reuse it for a shared-unpack
// pipeline: M=32 dst tiles (16 iters, 3 barriers each vs R5's 5x32=160):
//   scatter u8 counts -> block-wide convert A->Abf bf16 (once, not 8x/wave;
//   kills R5's 8192 redundant unpack VALU/thread) + rezero A in same pass ->
//   waves ds_read_b128 A-frags (XOR-swizzled granules) -> G MFMA (bh regs) ->
//   Gb hi/lo -> H3 MFMA (w2q regs) -> pp.  Numerics bit-identical (bf16 of
//   exact small ints, same MFMA order per C-column).
#define OFF_SORT 0
#define OFF_CS   16384
#define OFF_WSC  18440
#define OFF_WINT 20488
#define OFF_B1   22536
#define OFF_B2   23048
#define OFF_H1F  23568
#define OFF_SINT 89104
#define OFF_CSRA 23568
// phase-4 region (over dead h1F):
#define OFF_A    23568            // u8 [32][528]   = 16896
#define OFF_ABF  40464            // bf16[32][520]  = 33280 (XOR-swz granules)
#define OFF_GBH  73744            // bf16[32][136]  = 8704
#define OFF_GBL  82448            // bf16[32][136]  = 8704 (ends 91152)
#define FUSED_LDS 158736

__global__ __launch_bounds__(512,2) void k_fused(
      const int* __restrict__ src, const int* __restrict__ dst,
      const int* __restrict__ ntype, const float* __restrict__ b1,
      const float* __restrict__ b2, const unsigned short* __restrict__ EW1T,
      const unsigned short* __restrict__ W2F, float* __restrict__ out){
  extern __shared__ char smem[];
  unsigned short* sorted16 = (unsigned short*)(smem + OFF_SORT);
  int*   cs   = (int*)(smem + OFF_CS);
  float* wsc  = (float*)(smem + OFF_WSC);
  int*   wint = (int*)(smem + OFF_WINT);
  float* b1sh = (float*)(smem + OFF_B1);
  float* b2sh = (float*)(smem + OFF_B2);
  unsigned short* h1F = (unsigned short*)(smem + OFF_H1F);
  int*   Sint = (int*)(smem + OFF_SINT);        // [256][68], phases 2-3
  // phase-4 aliases (over dead h1F after bh hoist)
  unsigned char*  A   = (unsigned char*)(smem + OFF_A);    // [32][528]
  unsigned int*   A32 = (unsigned int*)(smem + OFF_A);
  unsigned short* Abf = (unsigned short*)(smem + OFF_ABF); // [32][520]
  unsigned short* gbh = (unsigned short*)(smem + OFF_GBH); // [32][136]
  unsigned short* gbl = (unsigned short*)(smem + OFF_GBL); // [32][136]
  float* red = (float*)(smem + OFF_A);          // [128] final alias
  // CSR-phase aliases (over h1F region, dead then)
  int* hist   = (int*)(smem + OFF_CSRA);        // [512]
  int* cursor = hist + 512;                     // [512]
  int* co     = cursor + 512;                   // [512]
  unsigned short* ntype_sh = (unsigned short*)(co + 512); // [512]

  const int b = blockIdx.x, tid = threadIdx.x;
  const int eb = b*EPG, nb = b*NPG;

  // ================= phase 1: CSR (all in LDS) =============================
  hist[tid]=0; co[tid]=0; ntype_sh[tid]=(unsigned short)ntype[nb+tid];
  if (tid<128){ b1sh[tid]=b1[tid]; b2sh[tid]=b2[tid]; }
  __syncthreads();
  int4 d4[4], s4[4];
  {
    const int4* dv = (const int4*)(dst+eb);
    const int4* sv = (const int4*)(src+eb);
    #pragma unroll
    for (int j=0;j<4;j++){
      d4[j]=dv[tid + j*512];
      s4[j]=sv[tid + j*512];
      atomicAdd(&hist[d4[j].x&(NPG-1)],1); atomicAdd(&hist[d4[j].y&(NPG-1)],1);
      atomicAdd(&hist[d4[j].z&(NPG-1)],1); atomicAdd(&hist[d4[j].w&(NPG-1)],1);
      atomicAdd(&co[s4[j].x&(NPG-1)],1);   atomicAdd(&co[s4[j].y&(NPG-1)],1);
      atomicAdd(&co[s4[j].z&(NPG-1)],1);   atomicAdd(&co[s4[j].w&(NPG-1)],1);
    }
  }
  __syncthreads();
  if (tid<64){
    int carry=0;
    #pragma unroll
    for (int c=0;c<8;c++){
      int sc=hist[64*c+tid];
      #pragma unroll
      for (int off=1;off<64;off<<=1){ int y=__shfl_up(sc,off); if (tid>=off) sc+=y; }
      cs[64*c+tid+1]=carry+sc;
      carry+=__shfl(sc,63);
    }
    if (tid==0) cs[0]=0;
  }
  __syncthreads();
  cursor[tid]=cs[tid];
  __syncthreads();
  #pragma unroll
  for (int j=0;j<4;j++){
    int dl, s, pos;
    dl=d4[j].x&(NPG-1); s=s4[j].x&(NPG-1);
    pos=atomicAdd(&cursor[dl],1);
    sorted16[pos]=(unsigned short)(((unsigned int)ntype_sh[s]<<9)|(unsigned int)s);
    dl=d4[j].y&(NPG-1); s=s4[j].y&(NPG-1);
    pos=atomicAdd(&cursor[dl],1);
    sorted16[pos]=(unsigned short)(((unsigned int)ntype_sh[s]<<9)|(unsigned int)s);
    dl=d4[j].z&(NPG-1); s=s4[j].z&(NPG-1);
    pos=atomicAdd(&cursor[dl],1);
    sorted16[pos]=(unsigned short)(((unsigned int)ntype_sh[s]<<9)|(unsigned int)s);
    dl=d4[j].w&(NPG-1); s=s4[j].w&(NPG-1);
    pos=atomicAdd(&cursor[dl],1);
    sorted16[pos]=(unsigned short)(((unsigned int)ntype_sh[s]<<9)|(unsigned int)s);
  }
  {                                             // out-degree isqrt
    int a=co[tid]; if(a<1)a=1;
    const float w = rsqrtf((float)a);
    wsc[tid]=w; wint[tid]=(int)(w*1048576.f);   // 2^20 fixed point
  }
  __syncthreads();                              // CSR done

  const int wave=tid>>6, lane=tid&63, l16=lane&15, quad=lane>>4;

  // ============ phases 2-3: layer-1 -> h1F (frag order), per src-half ======
  #pragma unroll 1
  for (int h=0; h<2; ++h){
    const int v0 = h*256;
    for (int i=tid; i<(256*68)/4; i+=512) ((f32x4*)Sint)[i]=(f32x4){0.f,0.f,0.f,0.f};
    __syncthreads();
    {                                           // edge scatter (2 thr/row)
      const int r = tid>>1, p = tid&1;
      const int e1 = cs[v0+r+1];
      for (int i=cs[v0+r]+p; i<e1; i+=2){
        const unsigned int e = sorted16[i];
        atomicAdd(&Sint[r*68 + (int)(e>>9)], wint[e&511]);
      }
    }
    __syncthreads();
    f32x4 acc1[2][8];
    #pragma unroll
    for (int rt=0;rt<2;rt++)
      #pragma unroll
      for (int nt=0;nt<8;nt++) acc1[rt][nt]=(f32x4){0.f,0.f,0.f,0.f};
    #pragma unroll
    for (int kh=0; kh<2; ++kh){
      s16x8 fh[2], fl[2];
      #pragma unroll
      for (int rt=0;rt<2;rt++){
        const int m = (wave*2+rt)*16 + l16;
        const int* sp = &Sint[m*68 + kh*32 + quad*8];
        union { s16x8 v; unsigned short u[8]; } hv, lv;
        #pragma unroll
        for (int j=0;j<8;j++){
          const float f = (float)sp[j] * (1.f/1048576.f);   // exact exp shift
          const unsigned short hi = f2bf(f);
          hv.u[j]=hi; lv.u[j]=f2bf(f - bf2f(hi));
        }
        fh[rt]=hv.v; fl[rt]=lv.v;
      }
      const int kc = kh*32 + quad*8;
      #pragma unroll
      for (int nt=0;nt<8;nt++){                 // one B-frag feeds hi AND lo
        s16x8 bfr=__builtin_bit_cast(s16x8,
            *(const uint4*)(EW1T + (size_t)(nt*16+l16)*64 + kc));
        acc1[0][nt]=__builtin_amdgcn_mfma_f32_16x16x32_bf16(fh[0],bfr,acc1[0][nt],0,0,0);
        acc1[1][nt]=__builtin_amdgcn_mfma_f32_16x16x32_bf16(fh[1],bfr,acc1[1][nt],0,0,0);
        acc1[0][nt]=__builtin_amdgcn_mfma_f32_16x16x32_bf16(fl[0],bfr,acc1[0][nt],0,0,0);
        acc1[1][nt]=__builtin_amdgcn_mfma_f32_16x16x32_bf16(fl[1],bfr,acc1[1][nt],0,0,0);
      }
    }
    float isq[2][4], os[2][4];
    #pragma unroll
    for (int rt=0;rt<2;rt++){
      const int mloc = (wave*2+rt)*16 + quad*4;
      #pragma unroll
      for (int r=0;r<4;r++){
        int d = cs[v0+mloc+r+1]-cs[v0+mloc+r]; if (d<1) d=1;
        isq[rt][r]=rsqrtf((float)d);
        os[rt][r]=wsc[v0+mloc+r];
      }
    }
    __syncthreads();       // ALL Sint reads done (h1F-half1 overlaps Sint!)
    // epilogue 1: h1 = relu(agg*isq+b1)*osc -> h1F in B-frag order
    #pragma unroll
    for (int rt=0;rt<2;rt++){
      const int ksg = h*8 + wave;               // k = v0+mloc+r -> ks tile
      const int kq  = rt*2 + (quad>>1);
      const int j0  = (quad&1)*4;
      #pragma unroll
      for (int nt=0;nt<8;nt++){
        const int col = nt*16+l16;
        const float bb1 = b1sh[col];
        ushort4 st;
        st.x = f2bf(fmaxf(acc1[rt][nt][0]*isq[rt][0]+bb1,0.f)*os[rt][0]);
        st.y = f2bf(fmaxf(acc1[rt][nt][1]*isq[rt][1]+bb1,0.f)*os[rt][1]);
        st.z = f2bf(fmaxf(acc1[rt][nt][2]*isq[rt][2]+bb1,0.f)*os[rt][2]);
        st.w = f2bf(fmaxf(acc1[rt][nt][3]*isq[rt][3]+bb1,0.f)*os[rt][3]);
        *(ushort4*)(h1F + ((((ksg*8+nt)*64) + kq*16 + l16)*8 + j0)) = st;
      }
    }
    __syncthreads();
  } // h

  // ============ phase 4: layer-2, M=32 tiles, shared unpack ================
  // hoist this wave's B-frags: h1F (nt=wave) and W2F (nt=wave) to registers
  s16x8 bh[16];
  #pragma unroll
  for (int ks=0;ks<16;ks++)
    bh[ks] = __builtin_bit_cast(s16x8,
        *(const uint4*)(h1F + (((ks*8+wave)*64 + lane)*8)));
  uint4 w2q[4];
  #pragma unroll
  for (int ks2=0;ks2<4;ks2++)
    w2q[ks2] = *(const uint4*)(W2F + (size_t)(((ks2*8+wave)*64)+lane)*8);
  const float bb2 = b2sh[wave*16+l16];
  __syncthreads();                     // all h1F hoist reads done; h1F now dead
  for (int i=tid; i<16896/16; i+=512) ((uint4*)A)[i]=(uint4){0u,0u,0u,0u};
  __syncthreads();                     // A zeroed before first scatter
  float pp = 0.f;
  const int crow = tid>>4, ccol = (tid&15)*32;  // convert-pass assignment

  #pragma unroll 1
  for (int dt=0; dt<16; ++dt){
    const int r0 = dt*32;
    {                                           // count scatter (16 thr/row)
      const int r = tid>>4, p = tid&15;
      const int e1 = cs[r0+r+1];
      for (int i=cs[r0+r]+p; i<e1; i+=16){
        const int s = (int)(sorted16[i] & 511u);
        atomicAdd(&A32[r*132 + (s>>2)], 1u<<((s&3)*8));
      }
    }
    __syncthreads();                            // (a) scatter done
    {   // convert A[crow][ccol..+31] u8 -> Abf bf16 (once per block) + rezero
      unsigned char* ap = A + crow*528 + ccol;
      const uint4 w0c = *(const uint4*)ap;
      const uint4 w1c = *(const uint4*)(ap+16);
      *(uint4*)ap = (uint4){0u,0u,0u,0u};
      *(uint4*)(ap+16) = (uint4){0u,0u,0u,0u};
      unsigned int wd[8] = {w0c.x,w0c.y,w0c.z,w0c.w,w1c.x,w1c.y,w1c.z,w1c.w};
      const int gb = (ccol>>3), sw = crow&7;    // granule base + XOR swizzle
      #pragma unroll
      for (int ch=0; ch<4; ++ch){               // 16B chunk: words 2ch,2ch+1
        uint4 st;
        unsigned int u0=wd[2*ch], u1=wd[2*ch+1];
        {
          const float g0=(float)( u0       &0xffu);
          const float g1=(float)((u0>> 8u) &0xffu);
          const float g2=(float)((u0>>16u) &0xffu);
          const float g3=(float)( u0>>24u        );
          st.x=__builtin_amdgcn_perm(__builtin_bit_cast(unsigned int,g1),
                                     __builtin_bit_cast(unsigned int,g0),0x07060302u);
          st.y=__builtin_amdgcn_perm(__builtin_bit_cast(unsigned int,g3),
                                     __builtin_bit_cast(unsigned int,g2),0x07060302u);
        }
        {
          const float g0=(float)( u1       &0xffu);
          const float g1=(float)((u1>> 8u) &0xffu);
          const float g2=(float)((u1>>16u) &0xffu);
          const float g3=(float)( u1>>24u        );
          st.z=__builtin_amdgcn_perm(__builtin_bit_cast(unsigned int,g1),
                                     __builtin_bit_cast(unsigned int,g0),0x07060302u);
          st.w=__builtin_amdgcn_perm(__builtin_bit_cast(unsigned int,g3),
                                     __builtin_bit_cast(unsigned int,g2),0x07060302u);
        }
        *(uint4*)(Abf + crow*520 + (((gb+ch)^sw)<<3)) = st;
      }
    }
    __syncthreads();                            // (b) Abf ready, A rezeroed
    // G = counts @ h1 (bh regs): per wave mt=0,1, its 16 cols (nt=wave)
    f32x4 g0=(f32x4){0.f,0.f,0.f,0.f}, g1=(f32x4){0.f,0.f,0.f,0.f};
    #pragma unroll
    for (int ks=0;ks<16;ks++){
      const int gsw = ((ks*4+quad) ^ (l16&7))<<3;
      const s16x8 a0 = __builtin_bit_cast(s16x8,
          *(const uint4*)(Abf + ( 0+l16)*520 + gsw));
      const s16x8 a1 = __builtin_bit_cast(s16x8,
          *(const uint4*)(Abf + (16+l16)*520 + gsw));
      g0=__builtin_amdgcn_mfma_f32_16x16x32_bf16(a0, bh[ks], g0,0,0,0);
      g1=__builtin_amdgcn_mfma_f32_16x16x32_bf16(a1, bh[ks], g1,0,0,0);
    }
    // Gb = bf16_hi/lo( G * isq ): rows mt*16+quad*4+ri, col wave*16+l16
    #pragma unroll
    for (int ri=0;ri<4;ri++){
      {
        const int row = quad*4+ri;
        int d = cs[r0+row+1]-cs[r0+row]; if (d<1) d=1;
        const float gs = g0[ri]*rsqrtf((float)d);
        const unsigned short hi = f2bf(gs);
        gbh[row*136 + wave*16+l16] = hi;
        gbl[row*136 + wave*16+l16] = f2bf(gs - bf2f(hi));
      }
      {
        const int row = 16+quad*4+ri;
        int d = cs[r0+row+1]-cs[r0+row]; if (d<1) d=1;
        const float gs = g1[ri]*rsqrtf((float)d);
        const unsigned short hi = f2bf(gs);
        gbh[row*136 + wave*16+l16] = hi;
        gbl[row*136 + wave*16+l16] = f2bf(gs - bf2f(hi));
      }
    }
    __syncthreads();                            // (c) Gb ready
    // H3 = Gb @ W2 (w2q regs), per mt, hi+lo
    f32x4 h30=(f32x4){0.f,0.f,0.f,0.f}, h31=(f32x4){0.f,0.f,0.f,0.f};
    #pragma unroll
    for (int ks2=0;ks2<4;ks2++){
      const int ko = ks2*32 + quad*8;
      h30=__builtin_amdgcn_mfma_f32_16x16x32_bf16(__builtin_bit_cast(s16x8,
          *(const uint4*)(gbh + ( 0+l16)*136 + ko)),
          __builtin_bit_cast(s16x8,w2q[ks2]), h30,0,0,0);
      h30=__builtin_amdgcn_mfma_f32_16x16x32_bf16(__builtin_bit_cast(s16x8,
          *(const uint4*)(gbl + ( 0+l16)*136 + ko)),
          __builtin_bit_cast(s16x8,w2q[ks2]), h30,0,0,0);
      h31=__builtin_amdgcn_mfma_f32_16x16x32_bf16(__builtin_bit_cast(s16x8,
          *(const uint4*)(gbh + (16+l16)*136 + ko)),
          __builtin_bit_cast(s16x8,w2q[ks2]), h31,0,0,0);
      h31=__builtin_amdgcn_mfma_f32_16x16x32_bf16(__builtin_bit_cast(s16x8,
          *(const uint4*)(gbl + (16+l16)*136 + ko)),
          __builtin_bit_cast(s16x8,w2q[ks2]), h31,0,0,0);
    }
    #pragma unroll
    for (int ri=0;ri<4;ri++){
      pp += fmaxf(h30[ri]+bb2, 0.f);
      pp += fmaxf(h31[ri]+bb2, 0.f);
    }
    // no barrier here: next scatter touches only A (rezeroed pre-(b));
    // next Gb write is separated from this H3 by barriers (a),(b)
  }

  // ============ final: column sums -> out (no atomics) =====================
  pp += __shfl_xor(pp,16);                      // sum the 4 quads' row groups
  pp += __shfl_xor(pp,32);
  __syncthreads();                              // all phase-4 LDS reads done
  if (quad==0) red[wave*16+l16] = pp;
  __syncthreads();
  if (tid<128) out[(size_t)b*128 + tid] = red[tid]*(1.f/512.f);
}

extern "C" void kernel_launch(void* const* d_in, const int* in_sizes, int n_in,
                              void* d_out, int out_size, void* d_ws, size_t ws_size,
                              hipStream_t stream){
  const int* node_feat = (const int*)d_in[0];
  const int* src = (const int*)d_in[1];
  const int* dst = (const int*)d_in[2];
  const float* emb = (const float*)d_in[3];
  const float* W1  = (const float*)d_in[4];
  const float* b1  = (const float*)d_in[5];
  const float* W2  = (const float*)d_in[6];
  const float* b2  = (const float*)d_in[7];

  char* ws = (char*)d_ws;
  unsigned short* EW1T = (unsigned short*)(ws);            // 16384 B
  unsigned short* W2F  = (unsigned short*)(ws + 16384);    // 32768 B

  (void)hipFuncSetAttribute(reinterpret_cast<const void*>(&k_fused),
        hipFuncAttributeMaxDynamicSharedMemorySize, FUSED_LDS);

  k_prep<<<GRAPHS,128,0,stream>>>(emb,W1,W2,EW1T,W2F);
  k_fused<<<GRAPHS,512,FUSED_LDS,stream>>>(src,dst,node_feat,b1,b2,EW1T,W2F,
        (float*)d_out);
}

// Round 7
// 149.699 us; speedup vs baseline: 2.7588x; 1.1119x over previous
//
#include <hip/hip_runtime.h>
#include <stdint.h>

#define GRAPHS 256
#define NPG    512
#define EPG    8192

typedef __attribute__((ext_vector_type(8))) short s16x8;
typedef __attribute__((ext_vector_type(4))) float f32x4;

__device__ __forceinline__ float bf2f(unsigned short u){
  union { unsigned int i; float f; } c; c.i = ((unsigned int)u)<<16; return c.f;
}
__device__ __forceinline__ unsigned short f2bf(float f){
  union { float f; unsigned int i; } c; c.f = f;
  unsigned int r = c.i + 0x7fffu + ((c.i>>16)&1u);   // RNE (software; do NOT
  return (unsigned short)(r>>16);                    // use v_cvt_pk_bf16_f32)
}

// ------- prep: EW1T (2 thr/entry) + W2F (1 thr/entry), 64 blocks -----------
__global__ __launch_bounds__(512) void k_prep(const float* __restrict__ emb,
      const float* __restrict__ W1, const float* __restrict__ W2,
      unsigned short* __restrict__ EW1T, unsigned short* __restrict__ W2F){
  const int bid = blockIdx.x, tid = threadIdx.x;
  if (bid < 32){                                 // EW1T: blocks 0..31
    const int gid = bid*256 + (tid>>1);          // entry 0..8191
    const int p = tid&1;
    const int t = gid>>7, c = gid&127;
    float acc=0.f;
    #pragma unroll 8
    for (int k=p*64;k<p*64+64;k++) acc += emb[t*128+k]*W1[k*128+c];
    const float other = __shfl_xor(acc,1);
    if (p==0) EW1T[c*64+t]=f2bf(acc+other);      // ordered: lo-half + hi-half
  } else {                                       // W2F: blocks 32..63
    const int i = (bid-32)*512 + tid;
    const int ks = i>>12, nt=(i>>9)&7, ln=(i>>3)&63, j=i&7;
    const int k = ks*32 + (ln>>4)*8 + j;
    const int n = nt*16 + (ln&15);
    W2F[i] = f2bf(W2[k*128+n]);
  }
}

// ---------------- fused kernel: 1 block = 1 graph, 1024 threads -------------
// R6 post-mortem: 512-thr version was occupancy-bound (2 waves/SIMD, ~60%
// stall) and my XOR swizzle CREATED 22.9M bank conflicts (row stride 65
// granules is odd -> linear layout is already the conflict-free one:
// bank = 4*((row+granule) mod 8), 2-way = free).  This version: 16 waves
// (4/SIMD), per-wave work halved in every phase, linear granules.
#define OFF_SORT 0
#define OFF_CS   16384
#define OFF_WSC  18440
#define OFF_WINT 20488
#define OFF_B1   22536
#define OFF_B2   23048
#define OFF_H1F  23568
#define OFF_SINT 89104
#define OFF_CSRA 23568
// phase-4 region (over dead h1F):
#define OFF_A    23568            // u8 [32][528]   = 16896
#define OFF_ABF  40464            // bf16[32][520]  = 33280 (LINEAR granules)
#define OFF_GBH  73744            // bf16[32][136]  = 8704
#define OFF_GBL  82448            // bf16[32][136]  = 8704 (ends 91152)
#define FUSED_LDS 158736

__global__ __launch_bounds__(1024,1) void k_fused(
      const int* __restrict__ src, const int* __restrict__ dst,
      const int* __restrict__ ntype, const float* __restrict__ b1,
      const float* __restrict__ b2, const unsigned short* __restrict__ EW1T,
      const unsigned short* __restrict__ W2F, float* __restrict__ out){
  extern __shared__ char smem[];
  unsigned short* sorted16 = (unsigned short*)(smem + OFF_SORT);
  int*   cs   = (int*)(smem + OFF_CS);
  float* wsc  = (float*)(smem + OFF_WSC);
  int*   wint = (int*)(smem + OFF_WINT);
  float* b1sh = (float*)(smem + OFF_B1);
  float* b2sh = (float*)(smem + OFF_B2);
  unsigned short* h1F = (unsigned short*)(smem + OFF_H1F);
  int*   Sint = (int*)(smem + OFF_SINT);        // [256][68], phases 2-3
  // phase-4 aliases (over dead h1F after bh hoist)
  unsigned char*  A   = (unsigned char*)(smem + OFF_A);    // [32][528]
  unsigned int*   A32 = (unsigned int*)(smem + OFF_A);
  unsigned short* Abf = (unsigned short*)(smem + OFF_ABF); // [32][520]
  unsigned short* gbh = (unsigned short*)(smem + OFF_GBH); // [32][136]
  unsigned short* gbl = (unsigned short*)(smem + OFF_GBL); // [32][136]
  float* red = (float*)(smem + OFF_A);          // [256] final alias
  // CSR-phase aliases (over h1F region, dead then)
  int* hist   = (int*)(smem + OFF_CSRA);        // [512]
  int* cursor = hist + 512;                     // [512]
  int* co     = cursor + 512;                   // [512]
  unsigned short* ntype_sh = (unsigned short*)(co + 512); // [512]

  const int b = blockIdx.x, tid = threadIdx.x;
  const int eb = b*EPG, nb = b*NPG;

  // ================= phase 1: CSR (all in LDS) =============================
  if (tid<512){ hist[tid]=0; co[tid]=0;
                ntype_sh[tid]=(unsigned short)ntype[nb+tid]; }
  if (tid<128){ b1sh[tid]=b1[tid]; b2sh[tid]=b2[tid]; }
  __syncthreads();
  int4 d4[2], s4[2];
  {
    const int4* dv = (const int4*)(dst+eb);
    const int4* sv = (const int4*)(src+eb);
    #pragma unroll
    for (int j=0;j<2;j++){
      d4[j]=dv[tid + j*1024];
      s4[j]=sv[tid + j*1024];
      atomicAdd(&hist[d4[j].x&(NPG-1)],1); atomicAdd(&hist[d4[j].y&(NPG-1)],1);
      atomicAdd(&hist[d4[j].z&(NPG-1)],1); atomicAdd(&hist[d4[j].w&(NPG-1)],1);
      atomicAdd(&co[s4[j].x&(NPG-1)],1);   atomicAdd(&co[s4[j].y&(NPG-1)],1);
      atomicAdd(&co[s4[j].z&(NPG-1)],1);   atomicAdd(&co[s4[j].w&(NPG-1)],1);
    }
  }
  __syncthreads();
  if (tid<64){
    int carry=0;
    #pragma unroll
    for (int c=0;c<8;c++){
      int sc=hist[64*c+tid];
      #pragma unroll
      for (int off=1;off<64;off<<=1){ int y=__shfl_up(sc,off); if (tid>=off) sc+=y; }
      cs[64*c+tid+1]=carry+sc;
      carry+=__shfl(sc,63);
    }
    if (tid==0) cs[0]=0;
  }
  __syncthreads();
  if (tid<512) cursor[tid]=cs[tid];
  __syncthreads();
  #pragma unroll
  for (int j=0;j<2;j++){
    int dl, s, pos;
    dl=d4[j].x&(NPG-1); s=s4[j].x&(NPG-1);
    pos=atomicAdd(&cursor[dl],1);
    sorted16[pos]=(unsigned short)(((unsigned int)ntype_sh[s]<<9)|(unsigned int)s);
    dl=d4[j].y&(NPG-1); s=s4[j].y&(NPG-1);
    pos=atomicAdd(&cursor[dl],1);
    sorted16[pos]=(unsigned short)(((unsigned int)ntype_sh[s]<<9)|(unsigned int)s);
    dl=d4[j].z&(NPG-1); s=s4[j].z&(NPG-1);
    pos=atomicAdd(&cursor[dl],1);
    sorted16[pos]=(unsigned short)(((unsigned int)ntype_sh[s]<<9)|(unsigned int)s);
    dl=d4[j].w&(NPG-1); s=s4[j].w&(NPG-1);
    pos=atomicAdd(&cursor[dl],1);
    sorted16[pos]=(unsigned short)(((unsigned int)ntype_sh[s]<<9)|(unsigned int)s);
  }
  if (tid<512){                                 // out-degree isqrt
    int a=co[tid]; if(a<1)a=1;
    const float w = rsqrtf((float)a);
    wsc[tid]=w; wint[tid]=(int)(w*1048576.f);   // 2^20 fixed point
  }
  __syncthreads();                              // CSR done

  const int wave=tid>>6, lane=tid&63, l16=lane&15, quad=lane>>4;

  // ============ phases 2-3: layer-1 -> h1F (frag order), per src-half ======
  // 16 waves: wave handles rows wave*16..+15 of the half (one 16-row tile).
  // MFMA chain per C-tile: kh0-hi, kh0-lo, kh1-hi, kh1-lo (= R6, bit-ident).
  #pragma unroll 1
  for (int h=0; h<2; ++h){
    const int v0 = h*256;
    for (int i=tid; i<(256*68)/4; i+=1024) ((f32x4*)Sint)[i]=(f32x4){0.f,0.f,0.f,0.f};
    __syncthreads();
    {                                           // edge scatter (4 thr/row)
      const int r = tid>>2, p = tid&3;
      const int e1 = cs[v0+r+1];
      for (int i=cs[v0+r]+p; i<e1; i+=4){
        const unsigned int e = sorted16[i];
        atomicAdd(&Sint[r*68 + (int)(e>>9)], wint[e&511]);
      }
    }
    __syncthreads();
    f32x4 acc1[8];
    #pragma unroll
    for (int nt=0;nt<8;nt++) acc1[nt]=(f32x4){0.f,0.f,0.f,0.f};
    #pragma unroll
    for (int kh=0; kh<2; ++kh){
      s16x8 fh, fl;
      {
        const int m = wave*16 + l16;
        const int* sp = &Sint[m*68 + kh*32 + quad*8];
        union { s16x8 v; unsigned short u[8]; } hv, lv;
        #pragma unroll
        for (int j=0;j<8;j++){
          const float f = (float)sp[j] * (1.f/1048576.f);   // exact exp shift
          const unsigned short hi = f2bf(f);
          hv.u[j]=hi; lv.u[j]=f2bf(f - bf2f(hi));
        }
        fh=hv.v; fl=lv.v;
      }
      const int kc = kh*32 + quad*8;
      #pragma unroll
      for (int nt=0;nt<8;nt++){                 // one B-frag feeds hi AND lo
        s16x8 bfr=__builtin_bit_cast(s16x8,
            *(const uint4*)(EW1T + (size_t)(nt*16+l16)*64 + kc));
        acc1[nt]=__builtin_amdgcn_mfma_f32_16x16x32_bf16(fh,bfr,acc1[nt],0,0,0);
        acc1[nt]=__builtin_amdgcn_mfma_f32_16x16x32_bf16(fl,bfr,acc1[nt],0,0,0);
      }
    }
    float isq[4], os[4];
    {
      const int mloc = wave*16 + quad*4;
      #pragma unroll
      for (int r=0;r<4;r++){
        int d = cs[v0+mloc+r+1]-cs[v0+mloc+r]; if (d<1) d=1;
        isq[r]=rsqrtf((float)d);
        os[r]=wsc[v0+mloc+r];
      }
    }
    __syncthreads();       // ALL Sint reads done (h1F-half1 overlaps Sint!)
    // epilogue 1: h1 = relu(agg*isq+b1)*osc -> h1F in B-frag order
    {
      const int ksg = h*8 + (wave>>1);          // k-row -> ks tile
      const int kq  = (wave&1)*2 + (quad>>1);
      const int j0  = (quad&1)*4;
      #pragma unroll
      for (int nt=0;nt<8;nt++){
        const int col = nt*16+l16;
        const float bb1 = b1sh[col];
        ushort4 st;
        st.x = f2bf(fmaxf(acc1[nt][0]*isq[0]+bb1,0.f)*os[0]);
        st.y = f2bf(fmaxf(acc1[nt][1]*isq[1]+bb1,0.f)*os[1]);
        st.z = f2bf(fmaxf(acc1[nt][2]*isq[2]+bb1,0.f)*os[2]);
        st.w = f2bf(fmaxf(acc1[nt][3]*isq[3]+bb1,0.f)*os[3]);
        *(ushort4*)(h1F + ((((ksg*8+nt)*64) + kq*16 + l16)*8 + j0)) = st;
      }
    }
    __syncthreads();
  } // h

  // ============ phase 4: layer-2, 16 dst tiles, 16 waves ===================
  // wave -> (mt = wave>>3, nt = wave&7); B-frags (h1F col-block nt, W2 col-
  // block nt) hoisted to regs; A-counts converted once block-wide.
  s16x8 bh[16];
  #pragma unroll
  for (int ks=0;ks<16;ks++)
    bh[ks] = __builtin_bit_cast(s16x8,
        *(const uint4*)(h1F + (((ks*8+(wave&7))*64 + lane)*8)));
  uint4 w2q[4];
  #pragma unroll
  for (int ks2=0;ks2<4;ks2++)
    w2q[ks2] = *(const uint4*)(W2F + (size_t)(((ks2*8+(wave&7))*64)+lane)*8);
  const float bb2 = b2sh[(wave&7)*16+l16];
  const int mt = wave>>3, ntw = wave&7;
  __syncthreads();                     // all h1F hoist reads done; h1F now dead
  for (int i=tid; i<16896/16; i+=1024) ((uint4*)A)[i]=(uint4){0u,0u,0u,0u};
  __syncthreads();                     // A zeroed before first scatter
  float pp = 0.f;
  const int crow = tid&31, ccol = (tid>>5)*16;  // convert-pass assignment

  #pragma unroll 1
  for (int dt=0; dt<16; ++dt){
    const int r0 = dt*32;
    {                                           // count scatter (32 thr/row)
      const int r = tid>>5, p = tid&31;
      const int e1 = cs[r0+r+1];
      for (int i=cs[r0+r]+p; i<e1; i+=32){
        const int s = (int)(sorted16[i] & 511u);
        atomicAdd(&A32[r*132 + (s>>2)], 1u<<((s&3)*8));
      }
    }
    __syncthreads();                            // (a) scatter done
    {   // convert A[crow][ccol..+15] u8 -> Abf bf16 (once/block) + rezero
      unsigned char* ap = A + crow*528 + ccol;
      const uint4 w0c = *(const uint4*)ap;
      *(uint4*)ap = (uint4){0u,0u,0u,0u};
      const int g0i = ccol>>3;                  // 2 linear granules g0i, g0i+1
      uint4 st0, st1;
      {
        const float g0=(float)( w0c.x       &0xffu);
        const float g1=(float)((w0c.x>> 8u) &0xffu);
        const float g2=(float)((w0c.x>>16u) &0xffu);
        const float g3=(float)( w0c.x>>24u        );
        st0.x=__builtin_amdgcn_perm(__builtin_bit_cast(unsigned int,g1),
                                    __builtin_bit_cast(unsigned int,g0),0x07060302u);
        st0.y=__builtin_amdgcn_perm(__builtin_bit_cast(unsigned int,g3),
                                    __builtin_bit_cast(unsigned int,g2),0x07060302u);
      }
      {
        const float g0=(float)( w0c.y       &0xffu);
        const float g1=(float)((w0c.y>> 8u) &0xffu);
        const float g2=(float)((w0c.y>>16u) &0xffu);
        const float g3=(float)( w0c.y>>24u        );
        st0.z=__builtin_amdgcn_perm(__builtin_bit_cast(unsigned int,g1),
                                    __builtin_bit_cast(unsigned int,g0),0x07060302u);
        st0.w=__builtin_amdgcn_perm(__builtin_bit_cast(unsigned int,g3),
                                    __builtin_bit_cast(unsigned int,g2),0x07060302u);
      }
      {
        const float g0=(float)( w0c.z       &0xffu);
        const float g1=(float)((w0c.z>> 8u) &0xffu);
        const float g2=(float)((w0c.z>>16u) &0xffu);
        const float g3=(float)( w0c.z>>24u        );
        st1.x=__builtin_amdgcn_perm(__builtin_bit_cast(unsigned int,g1),
                                    __builtin_bit_cast(unsigned int,g0),0x07060302u);
        st1.y=__builtin_amdgcn_perm(__builtin_bit_cast(unsigned int,g3),
                                    __builtin_bit_cast(unsigned int,g2),0x07060302u);
      }
      {
        const float g0=(float)( w0c.w       &0xffu);
        const float g1=(float)((w0c.w>> 8u) &0xffu);
        const float g2=(float)((w0c.w>>16u) &0xffu);
        const float g3=(float)( w0c.w>>24u        );
        st1.z=__builtin_amdgcn_perm(__builtin_bit_cast(unsigned int,g1),
                                    __builtin_bit_cast(unsigned int,g0),0x07060302u);
        st1.w=__builtin_amdgcn_perm(__builtin_bit_cast(unsigned int,g3),
                                    __builtin_bit_cast(unsigned int,g2),0x07060302u);
      }
      *(uint4*)(Abf + crow*520 + ((g0i  )<<3)) = st0;
      *(uint4*)(Abf + crow*520 + ((g0i+1)<<3)) = st1;
    }
    __syncthreads();                            // (b) Abf ready, A rezeroed
    // G = counts @ h1 (bh regs): wave's 16 rows (mt), 16 cols (ntw)
    f32x4 g0v=(f32x4){0.f,0.f,0.f,0.f};
    #pragma unroll
    for (int ks=0;ks<16;ks++){
      const s16x8 a0 = __builtin_bit_cast(s16x8,
          *(const uint4*)(Abf + (mt*16+l16)*520 + ((ks*4+quad)<<3)));
      g0v=__builtin_amdgcn_mfma_f32_16x16x32_bf16(a0, bh[ks], g0v,0,0,0);
    }
    // Gb = bf16_hi/lo( G * isq ): rows mt*16+quad*4+ri, col ntw*16+l16
    #pragma unroll
    for (int ri=0;ri<4;ri++){
      const int row = mt*16 + quad*4+ri;
      int d = cs[r0+row+1]-cs[r0+row]; if (d<1) d=1;
      const float gs = g0v[ri]*rsqrtf((float)d);
      const unsigned short hi = f2bf(gs);
      gbh[row*136 + ntw*16+l16] = hi;
      gbl[row*136 + ntw*16+l16] = f2bf(gs - bf2f(hi));
    }
    __syncthreads();                            // (c) Gb ready
    // H3 = Gb @ W2 (w2q regs): wave's 16 rows (mt), 16 cols (ntw), hi+lo
    f32x4 h30=(f32x4){0.f,0.f,0.f,0.f};
    #pragma unroll
    for (int ks2=0;ks2<4;ks2++){
      const int ko = ks2*32 + quad*8;
      h30=__builtin_amdgcn_mfma_f32_16x16x32_bf16(__builtin_bit_cast(s16x8,
          *(const uint4*)(gbh + (mt*16+l16)*136 + ko)),
          __builtin_bit_cast(s16x8,w2q[ks2]), h30,0,0,0);
      h30=__builtin_amdgcn_mfma_f32_16x16x32_bf16(__builtin_bit_cast(s16x8,
          *(const uint4*)(gbl + (mt*16+l16)*136 + ko)),
          __builtin_bit_cast(s16x8,w2q[ks2]), h30,0,0,0);
    }
    #pragma unroll
    for (int ri=0;ri<4;ri++) pp += fmaxf(h30[ri]+bb2, 0.f);
    // no barrier here: next scatter touches only A (rezeroed at convert);
    // next Gb write is separated from this H3's reads by barriers (a),(b)
  }

  // ============ final: column sums -> out (no atomics) =====================
  pp += __shfl_xor(pp,16);                      // sum quads (rows) within mt
  pp += __shfl_xor(pp,32);
  __syncthreads();                              // all phase-4 LDS reads done
  if (quad==0) red[wave*16+l16] = pp;           // red[c]=mt0, red[128+c]=mt1
  __syncthreads();
  if (tid<128) out[(size_t)b*128 + tid] = (red[tid]+red[128+tid])*(1.f/512.f);
}

extern "C" void kernel_launch(void* const* d_in, const int* in_sizes, int n_in,
                              void* d_out, int out_size, void* d_ws, size_t ws_size,
                              hipStream_t stream){
  const int* node_feat = (const int*)d_in[0];
  const int* src = (const int*)d_in[1];
  const int* dst = (const int*)d_in[2];
  const float* emb = (const float*)d_in[3];
  const float* W1  = (const float*)d_in[4];
  const float* b1  = (const float*)d_in[5];
  const float* W2  = (const float*)d_in[6];
  const float* b2  = (const float*)d_in[7];

  char* ws = (char*)d_ws;
  unsigned short* EW1T = (unsigned short*)(ws);            // 16384 B
  unsigned short* W2F  = (unsigned short*)(ws + 16384);    // 32768 B

  (void)hipFuncSetAttribute(reinterpret_cast<const void*>(&k_fused),
        hipFuncAttributeMaxDynamicSharedMemorySize, FUSED_LDS);

  k_prep<<<64,512,0,stream>>>(emb,W1,W2,EW1T,W2F);
  k_fused<<<GRAPHS,1024,FUSED_LDS,stream>>>(src,dst,node_feat,b1,b2,EW1T,W2F,
        (float*)d_out);
}

// Round 8
// 149.538 us; speedup vs baseline: 2.7618x; 1.0011x over previous
//
#include <hip/hip_runtime.h>
#include <stdint.h>

#define GRAPHS 256
#define NPG    512
#define EPG    8192

typedef __attribute__((ext_vector_type(8))) short s16x8;
typedef __attribute__((ext_vector_type(4))) float f32x4;

__device__ __forceinline__ float bf2f(unsigned short u){
  union { unsigned int i; float f; } c; c.i = ((unsigned int)u)<<16; return c.f;
}
__device__ __forceinline__ unsigned short f2bf(float f){
  union { float f; unsigned int i; } c; c.f = f;
  unsigned int r = c.i + 0x7fffu + ((c.i>>16)&1u);   // RNE (software; do NOT
  return (unsigned short)(r>>16);                    // use v_cvt_pk_bf16_f32)
}

// ------- prep: EW1T (2 thr/entry) + W2F (1 thr/entry), 64 blocks -----------
__global__ __launch_bounds__(512) void k_prep(const float* __restrict__ emb,
      const float* __restrict__ W1, const float* __restrict__ W2,
      unsigned short* __restrict__ EW1T, unsigned short* __restrict__ W2F){
  const int bid = blockIdx.x, tid = threadIdx.x;
  if (bid < 32){                                 // EW1T: blocks 0..31
    const int gid = bid*256 + (tid>>1);          // entry 0..8191
    const int p = tid&1;
    const int t = gid>>7, c = gid&127;
    float acc=0.f;
    #pragma unroll 8
    for (int k=p*64;k<p*64+64;k++) acc += emb[t*128+k]*W1[k*128+c];
    const float other = __shfl_xor(acc,1);
    if (p==0) EW1T[c*64+t]=f2bf(acc+other);      // ordered: lo-half + hi-half
  } else {                                       // W2F: blocks 32..63
    const int i = (bid-32)*512 + tid;
    const int ks = i>>12, nt=(i>>9)&7, ln=(i>>3)&63, j=i&7;
    const int k = ks*32 + (ln>>4)*8 + j;
    const int n = nt*16 + (ln&15);
    W2F[i] = f2bf(W2[k*128+n]);
  }
}

// ---------------- fused kernel: 1 block = 1 graph, 1024 threads -------------
// R7 post-mortem: __launch_bounds__(1024,1) let the backend pick an
// 8-waves/EU register target (VGPR_Count=64), spilling the 80-VGPR hoisted
// B-fragment state (bh[16]+w2q[4]) -> 40 MB scratch traffic/dispatch.
// A 16-wave workgroup is 4 waves/EU; declare it: (1024,4) -> 128-VGPR cap,
// peak demand ~110 fits.  NO other change this round (one-variable rule).
#define OFF_SORT 0
#define OFF_CS   16384
#define OFF_WSC  18440
#define OFF_WINT 20488
#define OFF_B1   22536
#define OFF_B2   23048
#define OFF_H1F  23568
#define OFF_SINT 89104
#define OFF_CSRA 23568
// phase-4 region (over dead h1F):
#define OFF_A    23568            // u8 [32][528]   = 16896
#define OFF_ABF  40464            // bf16[32][520]  = 33280 (LINEAR granules;
                                  //   row stride 65 granules is odd -> 2-way)
#define OFF_GBH  73744            // bf16[32][136]  = 8704
#define OFF_GBL  82448            // bf16[32][136]  = 8704 (ends 91152)
#define FUSED_LDS 158736

__global__ __launch_bounds__(1024,4) void k_fused(
      const int* __restrict__ src, const int* __restrict__ dst,
      const int* __restrict__ ntype, const float* __restrict__ b1,
      const float* __restrict__ b2, const unsigned short* __restrict__ EW1T,
      const unsigned short* __restrict__ W2F, float* __restrict__ out){
  extern __shared__ char smem[];
  unsigned short* sorted16 = (unsigned short*)(smem + OFF_SORT);
  int*   cs   = (int*)(smem + OFF_CS);
  float* wsc  = (float*)(smem + OFF_WSC);
  int*   wint = (int*)(smem + OFF_WINT);
  float* b1sh = (float*)(smem + OFF_B1);
  float* b2sh = (float*)(smem + OFF_B2);
  unsigned short* h1F = (unsigned short*)(smem + OFF_H1F);
  int*   Sint = (int*)(smem + OFF_SINT);        // [256][68], phases 2-3
  // phase-4 aliases (over dead h1F after bh hoist)
  unsigned char*  A   = (unsigned char*)(smem + OFF_A);    // [32][528]
  unsigned int*   A32 = (unsigned int*)(smem + OFF_A);
  unsigned short* Abf = (unsigned short*)(smem + OFF_ABF); // [32][520]
  unsigned short* gbh = (unsigned short*)(smem + OFF_GBH); // [32][136]
  unsigned short* gbl = (unsigned short*)(smem + OFF_GBL); // [32][136]
  float* red = (float*)(smem + OFF_A);          // [256] final alias
  // CSR-phase aliases (over h1F region, dead then)
  int* hist   = (int*)(smem + OFF_CSRA);        // [512]
  int* cursor = hist + 512;                     // [512]
  int* co     = cursor + 512;                   // [512]
  unsigned short* ntype_sh = (unsigned short*)(co + 512); // [512]

  const int b = blockIdx.x, tid = threadIdx.x;
  const int eb = b*EPG, nb = b*NPG;

  // ================= phase 1: CSR (all in LDS) =============================
  if (tid<512){ hist[tid]=0; co[tid]=0;
                ntype_sh[tid]=(unsigned short)ntype[nb+tid]; }
  if (tid<128){ b1sh[tid]=b1[tid]; b2sh[tid]=b2[tid]; }
  __syncthreads();
  int4 d4[2], s4[2];
  {
    const int4* dv = (const int4*)(dst+eb);
    const int4* sv = (const int4*)(src+eb);
    #pragma unroll
    for (int j=0;j<2;j++){
      d4[j]=dv[tid + j*1024];
      s4[j]=sv[tid + j*1024];
      atomicAdd(&hist[d4[j].x&(NPG-1)],1); atomicAdd(&hist[d4[j].y&(NPG-1)],1);
      atomicAdd(&hist[d4[j].z&(NPG-1)],1); atomicAdd(&hist[d4[j].w&(NPG-1)],1);
      atomicAdd(&co[s4[j].x&(NPG-1)],1);   atomicAdd(&co[s4[j].y&(NPG-1)],1);
      atomicAdd(&co[s4[j].z&(NPG-1)],1);   atomicAdd(&co[s4[j].w&(NPG-1)],1);
    }
  }
  __syncthreads();
  if (tid<64){
    int carry=0;
    #pragma unroll
    for (int c=0;c<8;c++){
      int sc=hist[64*c+tid];
      #pragma unroll
      for (int off=1;off<64;off<<=1){ int y=__shfl_up(sc,off); if (tid>=off) sc+=y; }
      cs[64*c+tid+1]=carry+sc;
      carry+=__shfl(sc,63);
    }
    if (tid==0) cs[0]=0;
  }
  __syncthreads();
  if (tid<512) cursor[tid]=cs[tid];
  __syncthreads();
  #pragma unroll
  for (int j=0;j<2;j++){
    int dl, s, pos;
    dl=d4[j].x&(NPG-1); s=s4[j].x&(NPG-1);
    pos=atomicAdd(&cursor[dl],1);
    sorted16[pos]=(unsigned short)(((unsigned int)ntype_sh[s]<<9)|(unsigned int)s);
    dl=d4[j].y&(NPG-1); s=s4[j].y&(NPG-1);
    pos=atomicAdd(&cursor[dl],1);
    sorted16[pos]=(unsigned short)(((unsigned int)ntype_sh[s]<<9)|(unsigned int)s);
    dl=d4[j].z&(NPG-1); s=s4[j].z&(NPG-1);
    pos=atomicAdd(&cursor[dl],1);
    sorted16[pos]=(unsigned short)(((unsigned int)ntype_sh[s]<<9)|(unsigned int)s);
    dl=d4[j].w&(NPG-1); s=s4[j].w&(NPG-1);
    pos=atomicAdd(&cursor[dl],1);
    sorted16[pos]=(unsigned short)(((unsigned int)ntype_sh[s]<<9)|(unsigned int)s);
  }
  if (tid<512){                                 // out-degree isqrt
    int a=co[tid]; if(a<1)a=1;
    const float w = rsqrtf((float)a);
    wsc[tid]=w; wint[tid]=(int)(w*1048576.f);   // 2^20 fixed point
  }
  __syncthreads();                              // CSR done

  const int wave=tid>>6, lane=tid&63, l16=lane&15, quad=lane>>4;

  // ============ phases 2-3: layer-1 -> h1F (frag order), per src-half ======
  // 16 waves: wave handles rows wave*16..+15 of the half (one 16-row tile).
  // MFMA chain per C-tile: kh0-hi, kh0-lo, kh1-hi, kh1-lo (= R6, bit-ident).
  #pragma unroll 1
  for (int h=0; h<2; ++h){
    const int v0 = h*256;
    for (int i=tid; i<(256*68)/4; i+=1024) ((f32x4*)Sint)[i]=(f32x4){0.f,0.f,0.f,0.f};
    __syncthreads();
    {                                           // edge scatter (4 thr/row)
      const int r = tid>>2, p = tid&3;
      const int e1 = cs[v0+r+1];
      for (int i=cs[v0+r]+p; i<e1; i+=4){
        const unsigned int e = sorted16[i];
        atomicAdd(&Sint[r*68 + (int)(e>>9)], wint[e&511]);
      }
    }
    __syncthreads();
    f32x4 acc1[8];
    #pragma unroll
    for (int nt=0;nt<8;nt++) acc1[nt]=(f32x4){0.f,0.f,0.f,0.f};
    #pragma unroll
    for (int kh=0; kh<2; ++kh){
      s16x8 fh, fl;
      {
        const int m = wave*16 + l16;
        const int* sp = &Sint[m*68 + kh*32 + quad*8];
        union { s16x8 v; unsigned short u[8]; } hv, lv;
        #pragma unroll
        for (int j=0;j<8;j++){
          const float f = (float)sp[j] * (1.f/1048576.f);   // exact exp shift
          const unsigned short hi = f2bf(f);
          hv.u[j]=hi; lv.u[j]=f2bf(f - bf2f(hi));
        }
        fh=hv.v; fl=lv.v;
      }
      const int kc = kh*32 + quad*8;
      #pragma unroll
      for (int nt=0;nt<8;nt++){                 // one B-frag feeds hi AND lo
        s16x8 bfr=__builtin_bit_cast(s16x8,
            *(const uint4*)(EW1T + (size_t)(nt*16+l16)*64 + kc));
        acc1[nt]=__builtin_amdgcn_mfma_f32_16x16x32_bf16(fh,bfr,acc1[nt],0,0,0);
        acc1[nt]=__builtin_amdgcn_mfma_f32_16x16x32_bf16(fl,bfr,acc1[nt],0,0,0);
      }
    }
    float isq[4], os[4];
    {
      const int mloc = wave*16 + quad*4;
      #pragma unroll
      for (int r=0;r<4;r++){
        int d = cs[v0+mloc+r+1]-cs[v0+mloc+r]; if (d<1) d=1;
        isq[r]=rsqrtf((float)d);
        os[r]=wsc[v0+mloc+r];
      }
    }
    __syncthreads();       // ALL Sint reads done (h1F-half1 overlaps Sint!)
    // epilogue 1: h1 = relu(agg*isq+b1)*osc -> h1F in B-frag order
    {
      const int ksg = h*8 + (wave>>1);          // k-row -> ks tile
      const int kq  = (wave&1)*2 + (quad>>1);
      const int j0  = (quad&1)*4;
      #pragma unroll
      for (int nt=0;nt<8;nt++){
        const int col = nt*16+l16;
        const float bb1 = b1sh[col];
        ushort4 st;
        st.x = f2bf(fmaxf(acc1[nt][0]*isq[0]+bb1,0.f)*os[0]);
        st.y = f2bf(fmaxf(acc1[nt][1]*isq[1]+bb1,0.f)*os[1]);
        st.z = f2bf(fmaxf(acc1[nt][2]*isq[2]+bb1,0.f)*os[2]);
        st.w = f2bf(fmaxf(acc1[nt][3]*isq[3]+bb1,0.f)*os[3]);
        *(ushort4*)(h1F + ((((ksg*8+nt)*64) + kq*16 + l16)*8 + j0)) = st;
      }
    }
    __syncthreads();
  } // h

  // ============ phase 4: layer-2, 16 dst tiles, 16 waves ===================
  // wave -> (mt = wave>>3, nt = wave&7); B-frags (h1F col-block nt, W2 col-
  // block nt) hoisted to regs; A-counts converted once block-wide.
  s16x8 bh[16];
  #pragma unroll
  for (int ks=0;ks<16;ks++)
    bh[ks] = __builtin_bit_cast(s16x8,
        *(const uint4*)(h1F + (((ks*8+(wave&7))*64 + lane)*8)));
  uint4 w2q[4];
  #pragma unroll
  for (int ks2=0;ks2<4;ks2++)
    w2q[ks2] = *(const uint4*)(W2F + (size_t)(((ks2*8+(wave&7))*64)+lane)*8);
  const float bb2 = b2sh[(wave&7)*16+l16];
  const int mt = wave>>3, ntw = wave&7;
  __syncthreads();                     // all h1F hoist reads done; h1F now dead
  for (int i=tid; i<16896/16; i+=1024) ((uint4*)A)[i]=(uint4){0u,0u,0u,0u};
  __syncthreads();                     // A zeroed before first scatter
  float pp = 0.f;
  const int crow = tid&31, ccol = (tid>>5)*16;  // convert-pass assignment

  #pragma unroll 1
  for (int dt=0; dt<16; ++dt){
    const int r0 = dt*32;
    {                                           // count scatter (32 thr/row)
      const int r = tid>>5, p = tid&31;
      const int e1 = cs[r0+r+1];
      for (int i=cs[r0+r]+p; i<e1; i+=32){
        const int s = (int)(sorted16[i] & 511u);
        atomicAdd(&A32[r*132 + (s>>2)], 1u<<((s&3)*8));
      }
    }
    __syncthreads();                            // (a) scatter done
    {   // convert A[crow][ccol..+15] u8 -> Abf bf16 (once/block) + rezero
      unsigned char* ap = A + crow*528 + ccol;
      const uint4 w0c = *(const uint4*)ap;
      *(uint4*)ap = (uint4){0u,0u,0u,0u};
      const int g0i = ccol>>3;                  // 2 linear granules g0i, g0i+1
      uint4 st0, st1;
      {
        const float g0=(float)( w0c.x       &0xffu);
        const float g1=(float)((w0c.x>> 8u) &0xffu);
        const float g2=(float)((w0c.x>>16u) &0xffu);
        const float g3=(float)( w0c.x>>24u        );
        st0.x=__builtin_amdgcn_perm(__builtin_bit_cast(unsigned int,g1),
                                    __builtin_bit_cast(unsigned int,g0),0x07060302u);
        st0.y=__builtin_amdgcn_perm(__builtin_bit_cast(unsigned int,g3),
                                    __builtin_bit_cast(unsigned int,g2),0x07060302u);
      }
      {
        const float g0=(float)( w0c.y       &0xffu);
        const float g1=(float)((w0c.y>> 8u) &0xffu);
        const float g2=(float)((w0c.y>>16u) &0xffu);
        const float g3=(float)( w0c.y>>24u        );
        st0.z=__builtin_amdgcn_perm(__builtin_bit_cast(unsigned int,g1),
                                    __builtin_bit_cast(unsigned int,g0),0x07060302u);
        st0.w=__builtin_amdgcn_perm(__builtin_bit_cast(unsigned int,g3),
                                    __builtin_bit_cast(unsigned int,g2),0x07060302u);
      }
      {
        const float g0=(float)( w0c.z       &0xffu);
        const float g1=(float)((w0c.z>> 8u) &0xffu);
        const float g2=(float)((w0c.z>>16u) &0xffu);
        const float g3=(float)( w0c.z>>24u        );
        st1.x=__builtin_amdgcn_perm(__builtin_bit_cast(unsigned int,g1),
                                    __builtin_bit_cast(unsigned int,g0),0x07060302u);
        st1.y=__builtin_amdgcn_perm(__builtin_bit_cast(unsigned int,g3),
                                    __builtin_bit_cast(unsigned int,g2),0x07060302u);
      }
      {
        const float g0=(float)( w0c.w       &0xffu);
        const float g1=(float)((w0c.w>> 8u) &0xffu);
        const float g2=(float)((w0c.w>>16u) &0xffu);
        const float g3=(float)( w0c.w>>24u        );
        st1.z=__builtin_amdgcn_perm(__builtin_bit_cast(unsigned int,g1),
                                    __builtin_bit_cast(unsigned int,g0),0x07060302u);
        st1.w=__builtin_amdgcn_perm(__builtin_bit_cast(unsigned int,g3),
                                    __builtin_bit_cast(unsigned int,g2),0x07060302u);
      }
      *(uint4*)(Abf + crow*520 + ((g0i  )<<3)) = st0;
      *(uint4*)(Abf + crow*520 + ((g0i+1)<<3)) = st1;
    }
    __syncthreads();                            // (b) Abf ready, A rezeroed
    // G = counts @ h1 (bh regs): wave's 16 rows (mt), 16 cols (ntw)
    f32x4 g0v=(f32x4){0.f,0.f,0.f,0.f};
    #pragma unroll
    for (int ks=0;ks<16;ks++){
      const s16x8 a0 = __builtin_bit_cast(s16x8,
          *(const uint4*)(Abf + (mt*16+l16)*520 + ((ks*4+quad)<<3)));
      g0v=__builtin_amdgcn_mfma_f32_16x16x32_bf16(a0, bh[ks], g0v,0,0,0);
    }
    // Gb = bf16_hi/lo( G * isq ): rows mt*16+quad*4+ri, col ntw*16+l16
    #pragma unroll
    for (int ri=0;ri<4;ri++){
      const int row = mt*16 + quad*4+ri;
      int d = cs[r0+row+1]-cs[r0+row]; if (d<1) d=1;
      const float gs = g0v[ri]*rsqrtf((float)d);
      const unsigned short hi = f2bf(gs);
      gbh[row*136 + ntw*16+l16] = hi;
      gbl[row*136 + ntw*16+l16] = f2bf(gs - bf2f(hi));
    }
    __syncthreads();                            // (c) Gb ready
    // H3 = Gb @ W2 (w2q regs): wave's 16 rows (mt), 16 cols (ntw), hi+lo
    f32x4 h30=(f32x4){0.f,0.f,0.f,0.f};
    #pragma unroll
    for (int ks2=0;ks2<4;ks2++){
      const int ko = ks2*32 + quad*8;
      h30=__builtin_amdgcn_mfma_f32_16x16x32_bf16(__builtin_bit_cast(s16x8,
          *(const uint4*)(gbh + (mt*16+l16)*136 + ko)),
          __builtin_bit_cast(s16x8,w2q[ks2]), h30,0,0,0);
      h30=__builtin_amdgcn_mfma_f32_16x16x32_bf16(__builtin_bit_cast(s16x8,
          *(const uint4*)(gbl + (mt*16+l16)*136 + ko)),
          __builtin_bit_cast(s16x8,w2q[ks2]), h30,0,0,0);
    }
    #pragma unroll
    for (int ri=0;ri<4;ri++) pp += fmaxf(h30[ri]+bb2, 0.f);
    // no barrier here: next scatter touches only A (rezeroed at convert);
    // next Gb write is separated from this H3's reads by barriers (a),(b)
  }

  // ============ final: column sums -> out (no atomics) =====================
  pp += __shfl_xor(pp,16);                      // sum quads (rows) within mt
  pp += __shfl_xor(pp,32);
  __syncthreads();                              // all phase-4 LDS reads done
  if (quad==0) red[wave*16+l16] = pp;           // red[c]=mt0, red[128+c]=mt1
  __syncthreads();
  if (tid<128) out[(size_t)b*128 + tid] = (red[tid]+red[128+tid])*(1.f/512.f);
}

extern "C" void kernel_launch(void* const* d_in, const int* in_sizes, int n_in,
                              void* d_out, int out_size, void* d_ws, size_t ws_size,
                              hipStream_t stream){
  const int* node_feat = (const int*)d_in[0];
  const int* src = (const int*)d_in[1];
  const int* dst = (const int*)d_in[2];
  const float* emb = (const float*)d_in[3];
  const float* W1  = (const float*)d_in[4];
  const float* b1  = (const float*)d_in[5];
  const float* W2  = (const float*)d_in[6];
  const float* b2  = (const float*)d_in[7];

  char* ws = (char*)d_ws;
  unsigned short* EW1T = (unsigned short*)(ws);            // 16384 B
  unsigned short* W2F  = (unsigned short*)(ws + 16384);    // 32768 B

  (void)hipFuncSetAttribute(reinterpret_cast<const void*>(&k_fused),
        hipFuncAttributeMaxDynamicSharedMemorySize, FUSED_LDS);

  k_prep<<<64,512,0,stream>>>(emb,W1,W2,EW1T,W2F);
  k_fused<<<GRAPHS,1024,FUSED_LDS,stream>>>(src,dst,node_feat,b1,b2,EW1T,W2F,
        (float*)d_out);
}